// Round 1
// baseline (3419.394 us; speedup 1.0000x reference)
//
#include <hip/hip_runtime.h>
#include <cstdint>
#include <cstddef>

constexpr int Bc = 2, Lc = 2048, DM = 1024, DI = 2048, DS = 16, DR = 64, NX = 96;
constexpr int BL = Bc * Lc; // 4096

// ---------------------------------------------------------------------------
// Generic tiled SGEMM: C[M,N] = A[M,K] @ B[N,K]^T  (+ optional bias/softplus)
// A row-major (lda), B row-major (ldb), C row-major (ldc).
// EPI: 0 = none, 1 = softplus(acc + bias[n])
// M must be a multiple of 128; N,K arbitrary with K % 16 == 0, (k-cols % 4 == 0).
// ---------------------------------------------------------------------------
template<int EPI>
__global__ __launch_bounds__(256) void gemm_bt(
    const float* __restrict__ A, const float* __restrict__ Bm,
    const float* __restrict__ bias, float* __restrict__ C,
    int M, int N, int K, int lda, int ldb, int ldc) {
  constexpr int BMt = 128, BNt = 128, BKt = 16;
  __shared__ float As[BKt][BMt + 4];
  __shared__ float Bs[BKt][BNt + 4];
  const int tid = threadIdx.x;
  const int bm = blockIdx.x * BMt;
  const int bn = blockIdx.y * BNt;
  const int lrow = tid >> 2;        // 0..63
  const int lcol = (tid & 3) * 4;   // 0,4,8,12
  const int tx = tid & 15, ty = tid >> 4;
  float acc[8][8] = {};
  for (int k0 = 0; k0 < K; k0 += BKt) {
    #pragma unroll
    for (int i = 0; i < 2; ++i) {
      int r = lrow + i * 64;
      float4 va = *reinterpret_cast<const float4*>(&A[(size_t)(bm + r) * lda + k0 + lcol]);
      As[lcol + 0][r] = va.x; As[lcol + 1][r] = va.y;
      As[lcol + 2][r] = va.z; As[lcol + 3][r] = va.w;
      int gn = bn + r;
      float4 vb = make_float4(0.f, 0.f, 0.f, 0.f);
      if (gn < N) vb = *reinterpret_cast<const float4*>(&Bm[(size_t)gn * ldb + k0 + lcol]);
      Bs[lcol + 0][r] = vb.x; Bs[lcol + 1][r] = vb.y;
      Bs[lcol + 2][r] = vb.z; Bs[lcol + 3][r] = vb.w;
    }
    __syncthreads();
    #pragma unroll
    for (int kk = 0; kk < BKt; ++kk) {
      float a[8], b[8];
      *reinterpret_cast<float4*>(&a[0]) = *reinterpret_cast<const float4*>(&As[kk][ty * 8]);
      *reinterpret_cast<float4*>(&a[4]) = *reinterpret_cast<const float4*>(&As[kk][ty * 8 + 4]);
      *reinterpret_cast<float4*>(&b[0]) = *reinterpret_cast<const float4*>(&Bs[kk][tx * 8]);
      *reinterpret_cast<float4*>(&b[4]) = *reinterpret_cast<const float4*>(&Bs[kk][tx * 8 + 4]);
      #pragma unroll
      for (int i = 0; i < 8; ++i)
        #pragma unroll
        for (int j = 0; j < 8; ++j)
          acc[i][j] = fmaf(a[i], b[j], acc[i][j]);
    }
    __syncthreads();
  }
  #pragma unroll
  for (int i = 0; i < 8; ++i) {
    int gm = bm + ty * 8 + i;
    #pragma unroll
    for (int j = 0; j < 8; ++j) {
      int gn = bn + tx * 8 + j;
      if (gn < N) {
        float v = acc[i][j];
        if (EPI == 1) {
          v += bias[gn];
          // stable softplus: max(x,0) + log1p(exp(-|x|))
          v = fmaxf(v, 0.f) + log1pf(expf(-fabsf(v)));
        }
        C[(size_t)gm * ldc + gn] = v;
      }
    }
  }
}

// ---------------------------------------------------------------------------
// Depthwise causal conv (D_CONV=4) + bias + SiLU.
// u = xz[:, 0:DI] (row stride 2*DI). Writes u_c[BL, DI].
// ---------------------------------------------------------------------------
__global__ __launch_bounds__(256) void conv_silu(
    const float* __restrict__ xz, const float* __restrict__ w,
    const float* __restrict__ bias, float* __restrict__ uc) {
  int idx = blockIdx.x * blockDim.x + threadIdx.x; // over BL*DI
  int d  = idx & (DI - 1);
  int bl = idx >> 11;          // /DI
  int b  = bl >> 11;           // /Lc
  int l  = bl & (Lc - 1);
  float4 wv = *reinterpret_cast<const float4*>(&w[d * 4]);
  float acc = bias[d];
  const float wk[4] = {wv.x, wv.y, wv.z, wv.w};
  #pragma unroll
  for (int k = 0; k < 4; ++k) {
    int ls = l - 3 + k;
    if (ls >= 0) acc = fmaf(xz[((size_t)(b * Lc + ls)) * (2 * DI) + d], wk[k], acc);
  }
  acc = acc / (1.f + expf(-acc)); // silu
  uc[idx] = acc;
}

// ---------------------------------------------------------------------------
// Selective scan. One thread per (b, d); 16 states in registers.
// Reads delta (softplus'ed), u_c, x_dbl (B_ssm/C_ssm), z (from xz), A_log, D.
// Writes gated y in-place over the delta buffer.
// ---------------------------------------------------------------------------
__global__ __launch_bounds__(256) void scan_kernel(
    const float* __restrict__ delta, const float* __restrict__ uc,
    const float* __restrict__ xdbl, const float* __restrict__ xz,
    const float* __restrict__ A_log, const float* __restrict__ Dv,
    float* __restrict__ yout) {
  int idx = blockIdx.x * blockDim.x + threadIdx.x; // over Bc*DI = 4096
  int d = idx & (DI - 1);
  int b = idx >> 11;
  float Av[DS];
  #pragma unroll
  for (int s = 0; s < DS; ++s) Av[s] = -expf(A_log[d * DS + s]);
  const float Dd = Dv[d];
  float h[DS] = {};
  for (int l = 0; l < Lc; ++l) {
    size_t bl = (size_t)b * Lc + l;
    float dt = delta[bl * DI + d];
    float ut = uc[bl * DI + d];
    const float* xe = &xdbl[bl * NX];
    float dtu = dt * ut;
    float y = 0.f;
    #pragma unroll
    for (int s = 0; s < DS; ++s) {
      float dA = expf(dt * Av[s]);
      float Bx = xe[DR + s];
      float Cx = xe[DR + DS + s];
      h[s] = fmaf(dA, h[s], dtu * Bx);
      y = fmaf(h[s], Cx, y);
    }
    float zt = xz[bl * (2 * DI) + DI + d];
    float gate = zt / (1.f + expf(-zt));
    y = (y + Dd * ut) * gate;
    yout[bl * DI + d] = y;
  }
}

// ---------------------------------------------------------------------------
extern "C" void kernel_launch(void* const* d_in, const int* in_sizes, int n_in,
                              void* d_out, int out_size, void* d_ws, size_t ws_size,
                              hipStream_t stream) {
  const float* x        = (const float*)d_in[0];
  const float* W_in     = (const float*)d_in[1];
  const float* conv_w   = (const float*)d_in[2];
  const float* conv_b   = (const float*)d_in[3];
  const float* W_xproj  = (const float*)d_in[4];
  const float* W_dtproj = (const float*)d_in[5];
  const float* dt_bias  = (const float*)d_in[6];
  const float* A_log    = (const float*)d_in[7];
  const float* Dv       = (const float*)d_in[8];
  const float* W_out    = (const float*)d_in[9];
  float* out = (float*)d_out;

  float* ws    = (float*)d_ws;
  float* xz    = ws;                               // BL * 2*DI   (64 MB)
  float* uc    = xz + (size_t)BL * 2 * DI;         // BL * DI     (32 MB)
  float* xdbl  = uc + (size_t)BL * DI;             // BL * NX     (1.5 MB)
  float* delta = xdbl + (size_t)BL * NX;           // BL * DI     (32 MB), becomes y

  // 1) in_proj: xz[BL, 2*DI] = x[BL, DM] @ W_in[2*DI, DM]^T
  gemm_bt<0><<<dim3(BL / 128, (2 * DI) / 128), 256, 0, stream>>>(
      x, W_in, nullptr, xz, BL, 2 * DI, DM, DM, DM, 2 * DI);

  // 2) depthwise causal conv + SiLU -> u_c[BL, DI]
  conv_silu<<<(BL * DI) / 256, 256, 0, stream>>>(xz, conv_w, conv_b, uc);

  // 3) x_proj: x_dbl[BL, 96] = u_c @ W_xproj^T
  gemm_bt<0><<<dim3(BL / 128, 1), 256, 0, stream>>>(
      uc, W_xproj, nullptr, xdbl, BL, NX, DI, DI, DI, NX);

  // 4) dt_proj + softplus: delta[BL, DI] = softplus(x_dbl[:, :64] @ W_dtproj^T + dt_bias)
  gemm_bt<1><<<dim3(BL / 128, DI / 128), 256, 0, stream>>>(
      xdbl, W_dtproj, dt_bias, delta, BL, DI, DR, NX, DR, DI);

  // 5) selective scan + skip + gate (writes gated y over delta buffer)
  scan_kernel<<<(Bc * DI) / 256, 256, 0, stream>>>(
      delta, uc, xdbl, xz, A_log, Dv, delta);

  // 6) out_proj: out[BL, DM] = y @ W_out^T
  gemm_bt<0><<<dim3(BL / 128, DM / 128), 256, 0, stream>>>(
      delta, W_out, nullptr, out, BL, DM, DI, DI, DI, DM);
}

// Round 2
// 2045.992 us; speedup vs baseline: 1.6713x; 1.6713x over previous
//
#include <hip/hip_runtime.h>
#include <cstdint>
#include <cstddef>

constexpr int Bc = 2, Lc = 2048, DM = 1024, DI = 2048, DS = 16, DR = 64, NX = 96;
constexpr int BL = Bc * Lc; // 4096

// ---------------------------------------------------------------------------
// Generic tiled SGEMM: C[M,N] = A[M,K] @ B[N,K]^T  (+ optional bias/softplus)
// A row-major (lda), B row-major (ldb), C row-major (ldc).
// EPI: 0 = none, 1 = softplus(acc + bias[n])
// M must be a multiple of 128; N,K arbitrary with K % 16 == 0, (k-cols % 4 == 0).
// ---------------------------------------------------------------------------
template<int EPI>
__global__ __launch_bounds__(256) void gemm_bt(
    const float* __restrict__ A, const float* __restrict__ Bm,
    const float* __restrict__ bias, float* __restrict__ C,
    int M, int N, int K, int lda, int ldb, int ldc) {
  constexpr int BMt = 128, BNt = 128, BKt = 16;
  __shared__ float As[BKt][BMt + 4];
  __shared__ float Bs[BKt][BNt + 4];
  const int tid = threadIdx.x;
  const int bm = blockIdx.x * BMt;
  const int bn = blockIdx.y * BNt;
  const int lrow = tid >> 2;        // 0..63
  const int lcol = (tid & 3) * 4;   // 0,4,8,12
  const int tx = tid & 15, ty = tid >> 4;
  float acc[8][8] = {};
  for (int k0 = 0; k0 < K; k0 += BKt) {
    #pragma unroll
    for (int i = 0; i < 2; ++i) {
      int r = lrow + i * 64;
      float4 va = *reinterpret_cast<const float4*>(&A[(size_t)(bm + r) * lda + k0 + lcol]);
      As[lcol + 0][r] = va.x; As[lcol + 1][r] = va.y;
      As[lcol + 2][r] = va.z; As[lcol + 3][r] = va.w;
      int gn = bn + r;
      float4 vb = make_float4(0.f, 0.f, 0.f, 0.f);
      if (gn < N) vb = *reinterpret_cast<const float4*>(&Bm[(size_t)gn * ldb + k0 + lcol]);
      Bs[lcol + 0][r] = vb.x; Bs[lcol + 1][r] = vb.y;
      Bs[lcol + 2][r] = vb.z; Bs[lcol + 3][r] = vb.w;
    }
    __syncthreads();
    #pragma unroll
    for (int kk = 0; kk < BKt; ++kk) {
      float a[8], b[8];
      *reinterpret_cast<float4*>(&a[0]) = *reinterpret_cast<const float4*>(&As[kk][ty * 8]);
      *reinterpret_cast<float4*>(&a[4]) = *reinterpret_cast<const float4*>(&As[kk][ty * 8 + 4]);
      *reinterpret_cast<float4*>(&b[0]) = *reinterpret_cast<const float4*>(&Bs[kk][tx * 8]);
      *reinterpret_cast<float4*>(&b[4]) = *reinterpret_cast<const float4*>(&Bs[kk][tx * 8 + 4]);
      #pragma unroll
      for (int i = 0; i < 8; ++i)
        #pragma unroll
        for (int j = 0; j < 8; ++j)
          acc[i][j] = fmaf(a[i], b[j], acc[i][j]);
    }
    __syncthreads();
  }
  #pragma unroll
  for (int i = 0; i < 8; ++i) {
    int gm = bm + ty * 8 + i;
    #pragma unroll
    for (int j = 0; j < 8; ++j) {
      int gn = bn + tx * 8 + j;
      if (gn < N) {
        float v = acc[i][j];
        if (EPI == 1) {
          v += bias[gn];
          // stable softplus: max(x,0) + log1p(exp(-|x|))
          v = fmaxf(v, 0.f) + log1pf(expf(-fabsf(v)));
        }
        C[(size_t)gm * ldc + gn] = v;
      }
    }
  }
}

// ---------------------------------------------------------------------------
// Depthwise causal conv (D_CONV=4) + bias + SiLU.
// u = xz[:, 0:DI] (row stride 2*DI). Writes u_c[BL, DI].
// ---------------------------------------------------------------------------
__global__ __launch_bounds__(256) void conv_silu(
    const float* __restrict__ xz, const float* __restrict__ w,
    const float* __restrict__ bias, float* __restrict__ uc) {
  int idx = blockIdx.x * blockDim.x + threadIdx.x; // over BL*DI
  int d  = idx & (DI - 1);
  int bl = idx >> 11;          // /DI
  int b  = bl >> 11;           // /Lc
  int l  = bl & (Lc - 1);
  float4 wv = *reinterpret_cast<const float4*>(&w[d * 4]);
  float acc = bias[d];
  const float wk[4] = {wv.x, wv.y, wv.z, wv.w};
  #pragma unroll
  for (int k = 0; k < 4; ++k) {
    int ls = l - 3 + k;
    if (ls >= 0) acc = fmaf(xz[((size_t)(b * Lc + ls)) * (2 * DI) + d], wk[k], acc);
  }
  acc = acc * __frcp_rn(1.f + __expf(-acc)); // silu
  uc[idx] = acc;
}

// ---------------------------------------------------------------------------
// Selective scan, one thread per (b, d, s). 16-lane groups share one (b, d);
// the 16 states advance independently; y = sum_s h[s]*C[s] via shfl butterfly.
// Software-pipelined: loads for l+1 issued before the exp->fma chain of l.
// delta_y (read dt / write gated y) intentionally NOT restrict: in-place.
// ---------------------------------------------------------------------------
__global__ __launch_bounds__(256) void scan_kernel(
    float* delta_y,
    const float* __restrict__ uc, const float* __restrict__ xdbl,
    const float* __restrict__ xz, const float* __restrict__ A_log,
    const float* __restrict__ Dv) {
  const int grp = threadIdx.x >> 4;           // 16 groups per block
  const int s   = threadIdx.x & 15;
  const int bd  = blockIdx.x * 16 + grp;      // 0 .. Bc*DI-1
  const int d   = bd & (DI - 1);
  const int b   = bd >> 11;

  const float Av = -__expf(A_log[d * DS + s]);
  const float Dd = Dv[d];
  const size_t base = (size_t)b * Lc;

  float h = 0.f;
  // prefetch l = 0
  float dt = delta_y[base * DI + d];
  float ut = uc[base * DI + d];
  float Bx = xdbl[base * NX + DR + s];
  float Cx = xdbl[base * NX + DR + DS + s];
  float zt = xz[base * (2 * DI) + DI + d];

  for (int l = 0; l < Lc; ++l) {
    const size_t bl  = base + l;
    const size_t bln = base + ((l + 1 < Lc) ? (l + 1) : l);
    // issue next-iteration loads early (latency hides under exp chain)
    float dtn = delta_y[bln * DI + d];
    float utn = uc[bln * DI + d];
    float Bxn = xdbl[bln * NX + DR + s];
    float Cxn = xdbl[bln * NX + DR + DS + s];
    float ztn = xz[bln * (2 * DI) + DI + d];

    float dA = __expf(dt * Av);
    h = fmaf(dA, h, dt * ut * Bx);
    float yp = h * Cx;
    #pragma unroll
    for (int m = 8; m >= 1; m >>= 1) yp += __shfl_xor(yp, m, 16);
    if (s == 0) {
      float gate = zt * __frcp_rn(1.f + __expf(-zt));
      delta_y[bl * DI + d] = (yp + Dd * ut) * gate;
    }
    dt = dtn; ut = utn; Bx = Bxn; Cx = Cxn; zt = ztn;
  }
}

// ---------------------------------------------------------------------------
extern "C" void kernel_launch(void* const* d_in, const int* in_sizes, int n_in,
                              void* d_out, int out_size, void* d_ws, size_t ws_size,
                              hipStream_t stream) {
  const float* x        = (const float*)d_in[0];
  const float* W_in     = (const float*)d_in[1];
  const float* conv_w   = (const float*)d_in[2];
  const float* conv_b   = (const float*)d_in[3];
  const float* W_xproj  = (const float*)d_in[4];
  const float* W_dtproj = (const float*)d_in[5];
  const float* dt_bias  = (const float*)d_in[6];
  const float* A_log    = (const float*)d_in[7];
  const float* Dv       = (const float*)d_in[8];
  const float* W_out    = (const float*)d_in[9];
  float* out = (float*)d_out;

  float* ws    = (float*)d_ws;
  float* xz    = ws;                               // BL * 2*DI   (64 MB)
  float* uc    = xz + (size_t)BL * 2 * DI;         // BL * DI     (32 MB)
  float* xdbl  = uc + (size_t)BL * DI;             // BL * NX     (1.5 MB)
  float* delta = xdbl + (size_t)BL * NX;           // BL * DI     (32 MB), becomes y

  // 1) in_proj: xz[BL, 2*DI] = x[BL, DM] @ W_in[2*DI, DM]^T
  gemm_bt<0><<<dim3(BL / 128, (2 * DI) / 128), 256, 0, stream>>>(
      x, W_in, nullptr, xz, BL, 2 * DI, DM, DM, DM, 2 * DI);

  // 2) depthwise causal conv + SiLU -> u_c[BL, DI]
  conv_silu<<<(BL * DI) / 256, 256, 0, stream>>>(xz, conv_w, conv_b, uc);

  // 3) x_proj: x_dbl[BL, 96] = u_c @ W_xproj^T
  gemm_bt<0><<<dim3(BL / 128, 1), 256, 0, stream>>>(
      uc, W_xproj, nullptr, xdbl, BL, NX, DI, DI, DI, NX);

  // 4) dt_proj + softplus: delta[BL, DI] = softplus(x_dbl[:, :64] @ W_dtproj^T + dt_bias)
  gemm_bt<1><<<dim3(BL / 128, DI / 128), 256, 0, stream>>>(
      xdbl, W_dtproj, dt_bias, delta, BL, DI, DR, NX, DR, DI);

  // 5) selective scan + skip + gate: one thread per (b,d,s)
  scan_kernel<<<(Bc * DI * DS) / 256, 256, 0, stream>>>(
      delta, uc, xdbl, xz, A_log, Dv);

  // 6) out_proj: out[BL, DM] = y @ W_out^T
  gemm_bt<0><<<dim3(BL / 128, DM / 128), 256, 0, stream>>>(
      delta, W_out, nullptr, out, BL, DM, DI, DI, DI, DM);
}

// Round 3
// 1460.021 us; speedup vs baseline: 2.3420x; 1.4013x over previous
//
#include <hip/hip_runtime.h>
#include <cstdint>
#include <cstddef>

constexpr int Bc = 2, Lc = 2048, DM = 1024, DI = 2048, DS = 16, DR = 64, NX = 96;
constexpr int BL = Bc * Lc;          // 4096
constexpr int NC = 32, CH = 64;      // chunks / chunk length (NC*CH == Lc)
constexpr int BDS = Bc * DI * DS;    // 65536

// ---------------------------------------------------------------------------
// Generic tiled SGEMM: C[M,N] = A[M,K] @ B[N,K]^T  (+ optional bias/softplus)
// ---------------------------------------------------------------------------
template<int EPI>
__global__ __launch_bounds__(256) void gemm_bt(
    const float* __restrict__ A, const float* __restrict__ Bm,
    const float* __restrict__ bias, float* __restrict__ C,
    int M, int N, int K, int lda, int ldb, int ldc) {
  constexpr int BMt = 128, BNt = 128, BKt = 16;
  __shared__ float As[BKt][BMt + 4];
  __shared__ float Bs[BKt][BNt + 4];
  const int tid = threadIdx.x;
  const int bm = blockIdx.x * BMt;
  const int bn = blockIdx.y * BNt;
  const int lrow = tid >> 2;        // 0..63
  const int lcol = (tid & 3) * 4;   // 0,4,8,12
  const int tx = tid & 15, ty = tid >> 4;
  float acc[8][8] = {};
  for (int k0 = 0; k0 < K; k0 += BKt) {
    #pragma unroll
    for (int i = 0; i < 2; ++i) {
      int r = lrow + i * 64;
      float4 va = *reinterpret_cast<const float4*>(&A[(size_t)(bm + r) * lda + k0 + lcol]);
      As[lcol + 0][r] = va.x; As[lcol + 1][r] = va.y;
      As[lcol + 2][r] = va.z; As[lcol + 3][r] = va.w;
      int gn = bn + r;
      float4 vb = make_float4(0.f, 0.f, 0.f, 0.f);
      if (gn < N) vb = *reinterpret_cast<const float4*>(&Bm[(size_t)gn * ldb + k0 + lcol]);
      Bs[lcol + 0][r] = vb.x; Bs[lcol + 1][r] = vb.y;
      Bs[lcol + 2][r] = vb.z; Bs[lcol + 3][r] = vb.w;
    }
    __syncthreads();
    #pragma unroll
    for (int kk = 0; kk < BKt; ++kk) {
      float a[8], b[8];
      *reinterpret_cast<float4*>(&a[0]) = *reinterpret_cast<const float4*>(&As[kk][ty * 8]);
      *reinterpret_cast<float4*>(&a[4]) = *reinterpret_cast<const float4*>(&As[kk][ty * 8 + 4]);
      *reinterpret_cast<float4*>(&b[0]) = *reinterpret_cast<const float4*>(&Bs[kk][tx * 8]);
      *reinterpret_cast<float4*>(&b[4]) = *reinterpret_cast<const float4*>(&Bs[kk][tx * 8 + 4]);
      #pragma unroll
      for (int i = 0; i < 8; ++i)
        #pragma unroll
        for (int j = 0; j < 8; ++j)
          acc[i][j] = fmaf(a[i], b[j], acc[i][j]);
    }
    __syncthreads();
  }
  #pragma unroll
  for (int i = 0; i < 8; ++i) {
    int gm = bm + ty * 8 + i;
    #pragma unroll
    for (int j = 0; j < 8; ++j) {
      int gn = bn + tx * 8 + j;
      if (gn < N) {
        float v = acc[i][j];
        if (EPI == 1) {
          v += bias[gn];
          v = fmaxf(v, 0.f) + log1pf(expf(-fabsf(v)));
        }
        C[(size_t)gm * ldc + gn] = v;
      }
    }
  }
}

// ---------------------------------------------------------------------------
// Depthwise causal conv (D_CONV=4) + bias + SiLU.
// ---------------------------------------------------------------------------
__global__ __launch_bounds__(256) void conv_silu(
    const float* __restrict__ xz, const float* __restrict__ w,
    const float* __restrict__ bias, float* __restrict__ uc) {
  int idx = blockIdx.x * blockDim.x + threadIdx.x; // over BL*DI
  int d  = idx & (DI - 1);
  int bl = idx >> 11;
  int b  = bl >> 11;
  int l  = bl & (Lc - 1);
  float4 wv = *reinterpret_cast<const float4*>(&w[d * 4]);
  float acc = bias[d];
  const float wk[4] = {wv.x, wv.y, wv.z, wv.w};
  #pragma unroll
  for (int k = 0; k < 4; ++k) {
    int ls = l - 3 + k;
    if (ls >= 0) acc = fmaf(xz[((size_t)(b * Lc + ls)) * (2 * DI) + d], wk[k], acc);
  }
  acc = acc * __frcp_rn(1.f + __expf(-acc)); // silu
  uc[idx] = acc;
}

// ---------------------------------------------------------------------------
// Chunked linear scan, pass A: per-(b,d,s,chunk) local scan from h=0.
// Stores Pa = prod(dA) and hA = local final state, layout [c][bds].
// Thread bits: s[0:4) d[4:15) b[15] c[16:21)
// ---------------------------------------------------------------------------
__global__ __launch_bounds__(256) void scan_chunk_local(
    const float* __restrict__ delta, const float* __restrict__ uc,
    const float* __restrict__ xdbl, const float* __restrict__ A_log,
    float* __restrict__ Pa, float* __restrict__ hA) {
  const int t = blockIdx.x * 256 + threadIdx.x;
  const int s = t & 15;
  const int d = (t >> 4) & (DI - 1);
  const int b = (t >> 15) & (Bc - 1);
  const int c = t >> 16;
  const float Av = -__expf(A_log[d * DS + s]);
  const size_t rowbase = (size_t)(b * Lc + c * CH);
  float h = 0.f, P = 1.f;
  float dt = delta[rowbase * DI + d];
  float ut = uc[rowbase * DI + d];
  float Bx = xdbl[rowbase * NX + DR + s];
  for (int l = 0; l < CH; ++l) {
    size_t rn = rowbase + ((l + 1 < CH) ? l + 1 : l);
    float dtn = delta[rn * DI + d];
    float utn = uc[rn * DI + d];
    float Bxn = xdbl[rn * NX + DR + s];
    float dA = __expf(dt * Av);
    h = fmaf(dA, h, dt * ut * Bx);
    P *= dA;
    dt = dtn; ut = utn; Bx = Bxn;
  }
  Pa[(size_t)c * BDS + (t & (BDS - 1))] = P;
  hA[(size_t)c * BDS + (t & (BDS - 1))] = h;
}

// ---------------------------------------------------------------------------
// Pass B: serial carry across chunks, fully coalesced, all in registers.
// h0[c] = carry-in state for chunk c.
// ---------------------------------------------------------------------------
__global__ __launch_bounds__(256) void scan_chunk_carry(
    const float* __restrict__ Pa, const float* __restrict__ hA,
    float* __restrict__ h0) {
  const int t = blockIdx.x * 256 + threadIdx.x; // over BDS
  float pa[NC], ha[NC];
  #pragma unroll
  for (int c = 0; c < NC; ++c) {
    pa[c] = Pa[(size_t)c * BDS + t];
    ha[c] = hA[(size_t)c * BDS + t];
  }
  float h = 0.f;
  #pragma unroll
  for (int c = 0; c < NC; ++c) {
    h0[(size_t)c * BDS + t] = h;
    h = fmaf(pa[c], h, ha[c]);
  }
}

// ---------------------------------------------------------------------------
// Pass C: re-run local scan from correct carry-in, reduce y over s (16-lane
// shfl), skip + gate, write gated y over the delta buffer (in-place; only
// lane s==0 writes, after all 16 lanes consumed dt for that l).
// ---------------------------------------------------------------------------
__global__ __launch_bounds__(256) void scan_chunk_final(
    float* delta_y, const float* __restrict__ uc,
    const float* __restrict__ xdbl, const float* __restrict__ xz,
    const float* __restrict__ A_log, const float* __restrict__ Dv,
    const float* __restrict__ h0) {
  const int t = blockIdx.x * 256 + threadIdx.x;
  const int s = t & 15;
  const int d = (t >> 4) & (DI - 1);
  const int b = (t >> 15) & (Bc - 1);
  const int c = t >> 16;
  const float Av = -__expf(A_log[d * DS + s]);
  const float Dd = Dv[d];
  float h = h0[(size_t)c * BDS + (t & (BDS - 1))];
  const size_t rowbase = (size_t)(b * Lc + c * CH);

  float dt = delta_y[rowbase * DI + d];
  float ut = uc[rowbase * DI + d];
  float Bx = xdbl[rowbase * NX + DR + s];
  float Cx = xdbl[rowbase * NX + DR + DS + s];
  float zt = xz[rowbase * (2 * DI) + DI + d];

  for (int l = 0; l < CH; ++l) {
    const size_t r  = rowbase + l;
    const size_t rn = rowbase + ((l + 1 < CH) ? l + 1 : l);
    float dtn = delta_y[rn * DI + d];
    float utn = uc[rn * DI + d];
    float Bxn = xdbl[rn * NX + DR + s];
    float Cxn = xdbl[rn * NX + DR + DS + s];
    float ztn = xz[rn * (2 * DI) + DI + d];

    float dA = __expf(dt * Av);
    h = fmaf(dA, h, dt * ut * Bx);
    float yp = h * Cx;
    #pragma unroll
    for (int m = 8; m >= 1; m >>= 1) yp += __shfl_xor(yp, m, 16);
    if (s == 0) {
      float gate = zt * __frcp_rn(1.f + __expf(-zt));
      delta_y[r * DI + d] = (yp + Dd * ut) * gate;
    }
    dt = dtn; ut = utn; Bx = Bxn; Cx = Cxn; zt = ztn;
  }
}

// ---------------------------------------------------------------------------
extern "C" void kernel_launch(void* const* d_in, const int* in_sizes, int n_in,
                              void* d_out, int out_size, void* d_ws, size_t ws_size,
                              hipStream_t stream) {
  const float* x        = (const float*)d_in[0];
  const float* W_in     = (const float*)d_in[1];
  const float* conv_w   = (const float*)d_in[2];
  const float* conv_b   = (const float*)d_in[3];
  const float* W_xproj  = (const float*)d_in[4];
  const float* W_dtproj = (const float*)d_in[5];
  const float* dt_bias  = (const float*)d_in[6];
  const float* A_log    = (const float*)d_in[7];
  const float* Dv       = (const float*)d_in[8];
  const float* W_out    = (const float*)d_in[9];
  float* out = (float*)d_out;

  float* ws    = (float*)d_ws;
  float* xz    = ws;                               // BL * 2*DI   (64 MB)
  float* uc    = xz + (size_t)BL * 2 * DI;         // BL * DI     (32 MB)
  float* xdbl  = uc + (size_t)BL * DI;             // BL * NX     (1.5 MB)
  float* delta = xdbl + (size_t)BL * NX;           // BL * DI     (32 MB), becomes y
  float* Pa    = delta + (size_t)BL * DI;          // NC*BDS      (8 MB)
  float* hAbuf = Pa + (size_t)NC * BDS;            // NC*BDS      (8 MB)
  float* h0buf = hAbuf + (size_t)NC * BDS;         // NC*BDS      (8 MB)

  // 1) in_proj
  gemm_bt<0><<<dim3(BL / 128, (2 * DI) / 128), 256, 0, stream>>>(
      x, W_in, nullptr, xz, BL, 2 * DI, DM, DM, DM, 2 * DI);

  // 2) depthwise causal conv + SiLU
  conv_silu<<<(BL * DI) / 256, 256, 0, stream>>>(xz, conv_w, conv_b, uc);

  // 3) x_proj
  gemm_bt<0><<<dim3(BL / 128, 1), 256, 0, stream>>>(
      uc, W_xproj, nullptr, xdbl, BL, NX, DI, DI, DI, NX);

  // 4) dt_proj + softplus
  gemm_bt<1><<<dim3(BL / 128, DI / 128), 256, 0, stream>>>(
      xdbl, W_dtproj, dt_bias, delta, BL, DI, DR, NX, DR, DI);

  // 5) chunked selective scan (3 passes)
  scan_chunk_local<<<(Bc * DI * DS * NC) / 256, 256, 0, stream>>>(
      delta, uc, xdbl, A_log, Pa, hAbuf);
  scan_chunk_carry<<<BDS / 256, 256, 0, stream>>>(Pa, hAbuf, h0buf);
  scan_chunk_final<<<(Bc * DI * DS * NC) / 256, 256, 0, stream>>>(
      delta, uc, xdbl, xz, A_log, Dv, h0buf);

  // 6) out_proj
  gemm_bt<0><<<dim3(BL / 128, DM / 128), 256, 0, stream>>>(
      delta, W_out, nullptr, out, BL, DM, DI, DI, DI, DM);
}

// Round 4
// 689.692 us; speedup vs baseline: 4.9579x; 2.1169x over previous
//
#include <hip/hip_runtime.h>
#include <cstdint>
#include <cstddef>

constexpr int Bc = 2, Lc = 2048, DM = 1024, DI = 2048, DS = 16, DR = 64, NX = 96;
constexpr int BL = Bc * Lc;          // 4096
constexpr int NC = 32, CH = 64;      // chunks / chunk length
constexpr int BDS = Bc * DI * DS;    // 65536

typedef __attribute__((ext_vector_type(8))) short bf16x8;
typedef __attribute__((ext_vector_type(4))) float f32x4;
typedef unsigned short u16;

__device__ __forceinline__ u16 f2b(float f) {          // fp32 -> bf16 (RNE)
  uint32_t u = __float_as_uint(f);
  return (u16)((u + 0x7FFFu + ((u >> 16) & 1u)) >> 16);
}
__device__ __forceinline__ float b2f(u16 h) {
  return __uint_as_float(((uint32_t)h) << 16);
}

// ---------------------------------------------------------------------------
// fp32 -> (hi, lo) bf16 planes, vectorized float4.
// ---------------------------------------------------------------------------
__global__ __launch_bounds__(256) void cvt_hilo(
    const float* __restrict__ in, u16* __restrict__ hi, u16* __restrict__ lo,
    int n4) {
  int i = blockIdx.x * 256 + threadIdx.x;
  if (i >= n4) return;
  float4 v = reinterpret_cast<const float4*>(in)[i];
  ushort4 H, L;
  H.x = f2b(v.x); L.x = f2b(v.x - b2f(H.x));
  H.y = f2b(v.y); L.y = f2b(v.y - b2f(H.y));
  H.z = f2b(v.z); L.z = f2b(v.z - b2f(H.z));
  H.w = f2b(v.w); L.w = f2b(v.w - b2f(H.w));
  reinterpret_cast<ushort4*>(hi)[i] = H;
  reinterpret_cast<ushort4*>(lo)[i] = L;
}

// W_xproj [96][2048] -> padded [128][2048] hi/lo planes (rows >=96 zero).
__global__ __launch_bounds__(256) void cvt_pad_wx(
    const float* __restrict__ w, u16* __restrict__ hi, u16* __restrict__ lo) {
  int i = blockIdx.x * 256 + threadIdx.x;      // over 128*2048/4 = 65536
  int f = i * 4;
  int row = f >> 11;
  ushort4 H, L;
  H.x = H.y = H.z = H.w = 0; L = H;
  if (row < 96) {
    float4 v = *reinterpret_cast<const float4*>(&w[f]);
    H.x = f2b(v.x); L.x = f2b(v.x - b2f(H.x));
    H.y = f2b(v.y); L.y = f2b(v.y - b2f(H.y));
    H.z = f2b(v.z); L.z = f2b(v.z - b2f(H.z));
    H.w = f2b(v.w); L.w = f2b(v.w - b2f(H.w));
  }
  reinterpret_cast<ushort4*>(hi)[i] = H;
  reinterpret_cast<ushort4*>(lo)[i] = L;
}

// ---------------------------------------------------------------------------
// Split-bf16 MFMA GEMM: C[M,N](fp32) = A[M,K] @ B[N,K]^T via hi/lo planes.
// 128x128 tile, BK=32, 4 waves (2x2), 16x16x32 bf16 MFMA, 3 passes
// (hi*hi + hi*lo + lo*hi). LDS staged with global_load_lds (16B), XOR-swizzled
// (slot ^= (row>>1)&3) via pre-swizzled global source + swizzled ds_read.
// EPI: 0 none, 1 softplus(acc + bias[n]).
// Requires M%128==0, K%32==0; N guarded (B planes must be padded to 128 rows).
// ---------------------------------------------------------------------------
__device__ __forceinline__ void stage_tile(
    const u16* __restrict__ g, u16* lds, int row0, int ld, int k0,
    int w, int lane) {
  #pragma unroll
  for (int i = 0; i < 2; ++i) {
    const int base = w * 1024 + i * 4096;          // wave-uniform byte base
    const int o = base + lane * 16;                // this lane's byte slot
    const int row = o >> 6;                        // 64B per row (32 bf16)
    const int sl = ((o >> 4) & 3) ^ ((row >> 1) & 3);  // inverse swizzle
    const u16* src = g + (size_t)(row0 + row) * ld + (k0 + sl * 8);
    __builtin_amdgcn_global_load_lds(
        (const __attribute__((address_space(1))) unsigned int*)src,
        (__attribute__((address_space(3))) unsigned int*)(lds + base / 2),
        16, 0, 0);
  }
}

__device__ __forceinline__ bf16x8 ld_frag(const u16* plane, int rowbase, int lane) {
  const int row = rowbase + (lane & 15);
  const int kb = (lane >> 4) ^ ((row >> 1) & 3);   // swizzled 16B slot
  return *reinterpret_cast<const bf16x8*>(
      reinterpret_cast<const char*>(plane) + row * 64 + kb * 16);
}

template<int EPI>
__global__ __launch_bounds__(256) void gemm_mfma(
    const u16* __restrict__ Ah, const u16* __restrict__ Al,
    const u16* __restrict__ Bh, const u16* __restrict__ Bl,
    const float* __restrict__ bias, float* __restrict__ C,
    int M, int N, int K, int lda, int ldb, int ldc) {
  __shared__ __align__(16) u16 lds[4][4096];       // Ah, Al, Bh, Bl tiles (8KB ea)
  const int tid = threadIdx.x;
  const int lane = tid & 63, w = tid >> 6;
  const int wr = w >> 1, wc = w & 1;
  const int bm = blockIdx.x * 128, bn = blockIdx.y * 128;

  f32x4 acc[4][4] = {};

  for (int k0 = 0; k0 < K; k0 += 32) {
    stage_tile(Ah, lds[0], bm, lda, k0, w, lane);
    stage_tile(Al, lds[1], bm, lda, k0, w, lane);
    stage_tile(Bh, lds[2], bn, ldb, k0, w, lane);
    stage_tile(Bl, lds[3], bn, ldb, k0, w, lane);
    __syncthreads();

    bf16x8 ah[4], al[4], bh[4], bl[4];
    #pragma unroll
    for (int m = 0; m < 4; ++m) {
      ah[m] = ld_frag(lds[0], wr * 64 + m * 16, lane);
      al[m] = ld_frag(lds[1], wr * 64 + m * 16, lane);
    }
    #pragma unroll
    for (int n = 0; n < 4; ++n) {
      bh[n] = ld_frag(lds[2], wc * 64 + n * 16, lane);
      bl[n] = ld_frag(lds[3], wc * 64 + n * 16, lane);
    }
    #pragma unroll
    for (int m = 0; m < 4; ++m)
      #pragma unroll
      for (int n = 0; n < 4; ++n)
        acc[m][n] = __builtin_amdgcn_mfma_f32_16x16x32_bf16(ah[m], bh[n], acc[m][n], 0, 0, 0);
    #pragma unroll
    for (int m = 0; m < 4; ++m)
      #pragma unroll
      for (int n = 0; n < 4; ++n)
        acc[m][n] = __builtin_amdgcn_mfma_f32_16x16x32_bf16(ah[m], bl[n], acc[m][n], 0, 0, 0);
    #pragma unroll
    for (int m = 0; m < 4; ++m)
      #pragma unroll
      for (int n = 0; n < 4; ++n)
        acc[m][n] = __builtin_amdgcn_mfma_f32_16x16x32_bf16(al[m], bh[n], acc[m][n], 0, 0, 0);
    __syncthreads();
  }

  // epilogue: C/D layout col = lane&15, row = (lane>>4)*4 + r (m89-verified)
  const int rbase = (lane >> 4) * 4;
  const int cidx = lane & 15;
  #pragma unroll
  for (int m = 0; m < 4; ++m) {
    int grow0 = bm + wr * 64 + m * 16 + rbase;
    #pragma unroll
    for (int n = 0; n < 4; ++n) {
      int gcol = bn + wc * 64 + n * 16 + cidx;
      if (gcol < N) {
        #pragma unroll
        for (int r = 0; r < 4; ++r) {
          float v = acc[m][n][r];
          if (EPI == 1) {
            v += bias[gcol];
            v = fmaxf(v, 0.f) + log1pf(expf(-fabsf(v)));
          }
          C[(size_t)(grow0 + r) * ldc + gcol] = v;
        }
      }
    }
  }
}

// ---------------------------------------------------------------------------
// Depthwise causal conv (D_CONV=4) + bias + SiLU -> u_c hi/lo bf16 planes.
// ---------------------------------------------------------------------------
__global__ __launch_bounds__(256) void conv_silu(
    const float* __restrict__ xz, const float* __restrict__ w,
    const float* __restrict__ bias, u16* __restrict__ uch,
    u16* __restrict__ ucl) {
  int idx = blockIdx.x * blockDim.x + threadIdx.x; // over BL*DI
  int d  = idx & (DI - 1);
  int bl = idx >> 11;
  int b  = bl >> 11;
  int l  = bl & (Lc - 1);
  float4 wv = *reinterpret_cast<const float4*>(&w[d * 4]);
  float acc = bias[d];
  const float wk[4] = {wv.x, wv.y, wv.z, wv.w};
  #pragma unroll
  for (int k = 0; k < 4; ++k) {
    int ls = l - 3 + k;
    if (ls >= 0) acc = fmaf(xz[((size_t)(b * Lc + ls)) * (2 * DI) + d], wk[k], acc);
  }
  acc = acc * __frcp_rn(1.f + __expf(-acc)); // silu
  u16 h = f2b(acc);
  uch[idx] = h;
  ucl[idx] = f2b(acc - b2f(h));
}

// ---------------------------------------------------------------------------
// Chunked linear scan, pass A: per-(b,d,s,chunk) local scan from h=0.
// u_c recombined from hi/lo planes. Thread bits: s[0:4) d[4:15) b[15] c[16:21)
// ---------------------------------------------------------------------------
__global__ __launch_bounds__(256) void scan_chunk_local(
    const float* __restrict__ delta, const u16* __restrict__ uch,
    const u16* __restrict__ ucl, const float* __restrict__ xdbl,
    const float* __restrict__ A_log, float* __restrict__ Pa,
    float* __restrict__ hA) {
  const int t = blockIdx.x * 256 + threadIdx.x;
  const int s = t & 15;
  const int d = (t >> 4) & (DI - 1);
  const int b = (t >> 15) & (Bc - 1);
  const int c = t >> 16;
  const float Av = -__expf(A_log[d * DS + s]);
  const size_t rowbase = (size_t)(b * Lc + c * CH);
  float h = 0.f, P = 1.f;
  float dt = delta[rowbase * DI + d];
  float ut = b2f(uch[rowbase * DI + d]) + b2f(ucl[rowbase * DI + d]);
  float Bx = xdbl[rowbase * NX + DR + s];
  for (int l = 0; l < CH; ++l) {
    size_t rn = rowbase + ((l + 1 < CH) ? l + 1 : l);
    float dtn = delta[rn * DI + d];
    float utn = b2f(uch[rn * DI + d]) + b2f(ucl[rn * DI + d]);
    float Bxn = xdbl[rn * NX + DR + s];
    float dA = __expf(dt * Av);
    h = fmaf(dA, h, dt * ut * Bx);
    P *= dA;
    dt = dtn; ut = utn; Bx = Bxn;
  }
  Pa[(size_t)c * BDS + (t & (BDS - 1))] = P;
  hA[(size_t)c * BDS + (t & (BDS - 1))] = h;
}

// ---------------------------------------------------------------------------
// Pass B: serial carry across chunks; h0 written in-place over Pa.
// ---------------------------------------------------------------------------
__global__ __launch_bounds__(256) void scan_chunk_carry(
    float* Pa_h0, const float* __restrict__ hA) {
  const int t = blockIdx.x * 256 + threadIdx.x; // over BDS
  float pa[NC], ha[NC];
  #pragma unroll
  for (int c = 0; c < NC; ++c) {
    pa[c] = Pa_h0[(size_t)c * BDS + t];
    ha[c] = hA[(size_t)c * BDS + t];
  }
  float h = 0.f;
  #pragma unroll
  for (int c = 0; c < NC; ++c) {
    Pa_h0[(size_t)c * BDS + t] = h;
    h = fmaf(pa[c], h, ha[c]);
  }
}

// ---------------------------------------------------------------------------
// Pass C: re-run local scan from carry-in, reduce y over s (16-lane shfl),
// skip + gate, write y as hi/lo bf16 planes (aliased over uch/ucl: each
// element's y write happens after its ut reads within the lockstep group).
// ---------------------------------------------------------------------------
__global__ __launch_bounds__(256) void scan_chunk_final(
    const float* __restrict__ delta, u16* uch, u16* ucl,
    const float* __restrict__ xdbl, const float* __restrict__ xz,
    const float* __restrict__ A_log, const float* __restrict__ Dv,
    const float* __restrict__ h0, u16* yh, u16* yl) {
  const int t = blockIdx.x * 256 + threadIdx.x;
  const int s = t & 15;
  const int d = (t >> 4) & (DI - 1);
  const int b = (t >> 15) & (Bc - 1);
  const int c = t >> 16;
  const float Av = -__expf(A_log[d * DS + s]);
  const float Dd = Dv[d];
  float h = h0[(size_t)c * BDS + (t & (BDS - 1))];
  const size_t rowbase = (size_t)(b * Lc + c * CH);

  float dt = delta[rowbase * DI + d];
  float ut = b2f(uch[rowbase * DI + d]) + b2f(ucl[rowbase * DI + d]);
  float Bx = xdbl[rowbase * NX + DR + s];
  float Cx = xdbl[rowbase * NX + DR + DS + s];
  float zt = xz[rowbase * (2 * DI) + DI + d];

  for (int l = 0; l < CH; ++l) {
    const size_t r  = rowbase + l;
    const size_t rn = rowbase + ((l + 1 < CH) ? l + 1 : l);
    float dtn = delta[rn * DI + d];
    float utn = b2f(uch[rn * DI + d]) + b2f(ucl[rn * DI + d]);
    float Bxn = xdbl[rn * NX + DR + s];
    float Cxn = xdbl[rn * NX + DR + DS + s];
    float ztn = xz[rn * (2 * DI) + DI + d];

    float dA = __expf(dt * Av);
    h = fmaf(dA, h, dt * ut * Bx);
    float yp = h * Cx;
    #pragma unroll
    for (int m = 8; m >= 1; m >>= 1) yp += __shfl_xor(yp, m, 16);
    if (s == 0) {
      float gate = zt * __frcp_rn(1.f + __expf(-zt));
      float y = (yp + Dd * ut) * gate;
      u16 hh = f2b(y);
      yh[r * DI + d] = hh;
      yl[r * DI + d] = f2b(y - b2f(hh));
    }
    dt = dtn; ut = utn; Bx = Bxn; Cx = Cxn; zt = ztn;
  }
}

// ---------------------------------------------------------------------------
extern "C" void kernel_launch(void* const* d_in, const int* in_sizes, int n_in,
                              void* d_out, int out_size, void* d_ws, size_t ws_size,
                              hipStream_t stream) {
  const float* x        = (const float*)d_in[0];
  const float* W_in     = (const float*)d_in[1];
  const float* conv_w   = (const float*)d_in[2];
  const float* conv_b   = (const float*)d_in[3];
  const float* W_xproj  = (const float*)d_in[4];
  const float* W_dtproj = (const float*)d_in[5];
  const float* dt_bias  = (const float*)d_in[6];
  const float* A_log    = (const float*)d_in[7];
  const float* Dv       = (const float*)d_in[8];
  const float* W_out    = (const float*)d_in[9];
  float* out = (float*)d_out;

  char* W = (char*)d_ws;
  size_t off = 0;
  float* xz  = (float*)(W + off);  off += (size_t)BL * 4096 * 4;    // 64 MB
  size_t delta_off = off;
  u16* xh   = (u16*)(W + off);     off += (size_t)BL * DM * 2;      // 8 MB
  u16* xl   = (u16*)(W + off);     off += (size_t)BL * DM * 2;      // 8 MB
  u16* Wih  = (u16*)(W + off);     off += (size_t)(2 * DI) * DM * 2;// 8 MB
  u16* Wil  = (u16*)(W + off);     off += (size_t)(2 * DI) * DM * 2;// 8 MB
  float* delta = (float*)(W + delta_off);  // 32 MB, aliases xh..Wil (dead post in_proj)
  u16* uch  = (u16*)(W + off);     off += (size_t)BL * DI * 2;      // 16 MB
  u16* ucl  = (u16*)(W + off);     off += (size_t)BL * DI * 2;      // 16 MB
  u16* Wxh  = (u16*)(W + off);     off += (size_t)128 * DI * 2;     // 0.5 MB (padded)
  u16* Wxl  = (u16*)(W + off);     off += (size_t)128 * DI * 2;
  float* xdbl = (float*)(W + off); off += (size_t)BL * NX * 4;      // 1.5 MB
  u16* xdh  = (u16*)(W + off);     off += (size_t)BL * NX * 2;
  u16* xdl  = (u16*)(W + off);     off += (size_t)BL * NX * 2;
  u16* Wdh  = (u16*)(W + off);     off += (size_t)DI * DR * 2;
  u16* Wdl  = (u16*)(W + off);     off += (size_t)DI * DR * 2;
  u16* Woh  = (u16*)(W + off);     off += (size_t)DM * DI * 2;      // 4 MB
  u16* Wol  = (u16*)(W + off);     off += (size_t)DM * DI * 2;      // 4 MB
  float* Pa = (float*)(W + off);   off += (size_t)NC * BDS * 4;     // 8 MB
  float* hA = (float*)(W + off);   off += (size_t)NC * BDS * 4;     // 8 MB
  float* h0 = Pa;                  // pass B writes h0 in-place over Pa
  u16* yh = uch;                   // pass C writes y over uc planes (safe)
  u16* yl = ucl;

  // 0) conversions to bf16 hi/lo planes
  cvt_hilo<<<(BL * DM / 4 + 255) / 256, 256, 0, stream>>>(x, xh, xl, BL * DM / 4);
  cvt_hilo<<<(2 * DI * DM / 4 + 255) / 256, 256, 0, stream>>>(W_in, Wih, Wil, 2 * DI * DM / 4);
  cvt_pad_wx<<<(128 * DI / 4) / 256, 256, 0, stream>>>(W_xproj, Wxh, Wxl);
  cvt_hilo<<<(DI * DR / 4 + 255) / 256, 256, 0, stream>>>(W_dtproj, Wdh, Wdl, DI * DR / 4);
  cvt_hilo<<<(DM * DI / 4 + 255) / 256, 256, 0, stream>>>(W_out, Woh, Wol, DM * DI / 4);

  // 1) in_proj: xz = x @ W_in^T   (M=4096, N=4096, K=1024)
  gemm_mfma<0><<<dim3(BL / 128, (2 * DI) / 128), 256, 0, stream>>>(
      xh, xl, Wih, Wil, nullptr, xz, BL, 2 * DI, DM, DM, DM, 2 * DI);

  // 2) depthwise causal conv + SiLU -> uc hi/lo planes
  conv_silu<<<(BL * DI) / 256, 256, 0, stream>>>(xz, conv_w, conv_b, uch, ucl);

  // 3) x_proj: xdbl = u_c @ W_xproj^T  (N=96, padded B planes)
  gemm_mfma<0><<<dim3(BL / 128, 1), 256, 0, stream>>>(
      uch, ucl, Wxh, Wxl, nullptr, xdbl, BL, NX, DI, DI, DI, NX);

  // 3b) xdbl -> hi/lo (dt_proj A operand)
  cvt_hilo<<<(BL * NX / 4 + 255) / 256, 256, 0, stream>>>(xdbl, xdh, xdl, BL * NX / 4);

  // 4) dt_proj + softplus: delta = softplus(xdbl[:, :64] @ W_dtproj^T + bias)
  gemm_mfma<1><<<dim3(BL / 128, DI / 128), 256, 0, stream>>>(
      xdh, xdl, Wdh, Wdl, dt_bias, delta, BL, DI, DR, NX, DR, DI);

  // 5) chunked selective scan (3 passes)
  scan_chunk_local<<<(Bc * DI * DS * NC) / 256, 256, 0, stream>>>(
      delta, uch, ucl, xdbl, A_log, Pa, hA);
  scan_chunk_carry<<<BDS / 256, 256, 0, stream>>>(Pa, hA);
  scan_chunk_final<<<(Bc * DI * DS * NC) / 256, 256, 0, stream>>>(
      delta, uch, ucl, xdbl, xz, A_log, Dv, h0, yh, yl);

  // 6) out_proj: out = y @ W_out^T  (M=4096, N=1024, K=2048)
  gemm_mfma<0><<<dim3(BL / 128, DM / 128), 256, 0, stream>>>(
      yh, yl, Woh, Wol, nullptr, out, BL, DM, DI, DI, DI, DM);
}

// Round 5
// 552.790 us; speedup vs baseline: 6.1857x; 1.2477x over previous
//
#include <hip/hip_runtime.h>
#include <cstdint>
#include <cstddef>

constexpr int Bc = 2, Lc = 2048, DM = 1024, DI = 2048, DS = 16, DR = 64, NX = 96;
constexpr int BL = Bc * Lc;          // 4096
constexpr int NC = 32, CH = 64;      // chunks / chunk length
constexpr int BDS = Bc * DI * DS;    // 65536
constexpr float LOG2E = 1.44269504f;

typedef __attribute__((ext_vector_type(8))) short bf16x8;
typedef __attribute__((ext_vector_type(4))) float f32x4;
typedef unsigned short u16;

__device__ __forceinline__ u16 f2b(float f) {          // fp32 -> bf16 (RNE)
  uint32_t u = __float_as_uint(f);
  return (u16)((u + 0x7FFFu + ((u >> 16) & 1u)) >> 16);
}
__device__ __forceinline__ float b2f(u16 h) {
  return __uint_as_float(((uint32_t)h) << 16);
}

// ---------------------------------------------------------------------------
// fp32 -> (hi, lo) bf16 planes, vectorized float4.
// ---------------------------------------------------------------------------
__global__ __launch_bounds__(256) void cvt_hilo(
    const float* __restrict__ in, u16* __restrict__ hi, u16* __restrict__ lo,
    int n4) {
  int i = blockIdx.x * 256 + threadIdx.x;
  if (i >= n4) return;
  float4 v = reinterpret_cast<const float4*>(in)[i];
  ushort4 H, L;
  H.x = f2b(v.x); L.x = f2b(v.x - b2f(H.x));
  H.y = f2b(v.y); L.y = f2b(v.y - b2f(H.y));
  H.z = f2b(v.z); L.z = f2b(v.z - b2f(H.z));
  H.w = f2b(v.w); L.w = f2b(v.w - b2f(H.w));
  reinterpret_cast<ushort4*>(hi)[i] = H;
  reinterpret_cast<ushort4*>(lo)[i] = L;
}

// W_xproj [96][2048] -> padded [128][2048] hi/lo planes (rows >=96 zero).
__global__ __launch_bounds__(256) void cvt_pad_wx(
    const float* __restrict__ w, u16* __restrict__ hi, u16* __restrict__ lo) {
  int i = blockIdx.x * 256 + threadIdx.x;      // over 128*2048/4 = 65536
  int f = i * 4;
  int row = f >> 11;
  ushort4 H, L;
  H.x = H.y = H.z = H.w = 0; L = H;
  if (row < 96) {
    float4 v = *reinterpret_cast<const float4*>(&w[f]);
    H.x = f2b(v.x); L.x = f2b(v.x - b2f(H.x));
    H.y = f2b(v.y); L.y = f2b(v.y - b2f(H.y));
    H.z = f2b(v.z); L.z = f2b(v.z - b2f(H.z));
    H.w = f2b(v.w); L.w = f2b(v.w - b2f(H.w));
  }
  reinterpret_cast<ushort4*>(hi)[i] = H;
  reinterpret_cast<ushort4*>(lo)[i] = L;
}

// ---------------------------------------------------------------------------
// Split-bf16 MFMA GEMM: C[M,N](fp32) = A[M,K] @ B[N,K]^T via hi/lo planes.
// 128x128 tile, BK=32, 4 waves (2x2), 16x16x32 bf16 MFMA, 3 passes.
// ---------------------------------------------------------------------------
__device__ __forceinline__ void stage_tile(
    const u16* __restrict__ g, u16* lds, int row0, int ld, int k0,
    int w, int lane) {
  #pragma unroll
  for (int i = 0; i < 2; ++i) {
    const int base = w * 1024 + i * 4096;          // wave-uniform byte base
    const int o = base + lane * 16;                // this lane's byte slot
    const int row = o >> 6;                        // 64B per row (32 bf16)
    const int sl = ((o >> 4) & 3) ^ ((row >> 1) & 3);  // inverse swizzle
    const u16* src = g + (size_t)(row0 + row) * ld + (k0 + sl * 8);
    __builtin_amdgcn_global_load_lds(
        (const __attribute__((address_space(1))) unsigned int*)src,
        (__attribute__((address_space(3))) unsigned int*)(lds + base / 2),
        16, 0, 0);
  }
}

__device__ __forceinline__ bf16x8 ld_frag(const u16* plane, int rowbase, int lane) {
  const int row = rowbase + (lane & 15);
  const int kb = (lane >> 4) ^ ((row >> 1) & 3);   // swizzled 16B slot
  return *reinterpret_cast<const bf16x8*>(
      reinterpret_cast<const char*>(plane) + row * 64 + kb * 16);
}

template<int EPI>
__global__ __launch_bounds__(256) void gemm_mfma(
    const u16* __restrict__ Ah, const u16* __restrict__ Al,
    const u16* __restrict__ Bh, const u16* __restrict__ Bl,
    const float* __restrict__ bias, float* __restrict__ C,
    int M, int N, int K, int lda, int ldb, int ldc) {
  __shared__ __align__(16) u16 lds[4][4096];       // Ah, Al, Bh, Bl tiles (8KB ea)
  const int tid = threadIdx.x;
  const int lane = tid & 63, w = tid >> 6;
  const int wr = w >> 1, wc = w & 1;
  const int bm = blockIdx.x * 128, bn = blockIdx.y * 128;

  f32x4 acc[4][4] = {};

  for (int k0 = 0; k0 < K; k0 += 32) {
    stage_tile(Ah, lds[0], bm, lda, k0, w, lane);
    stage_tile(Al, lds[1], bm, lda, k0, w, lane);
    stage_tile(Bh, lds[2], bn, ldb, k0, w, lane);
    stage_tile(Bl, lds[3], bn, ldb, k0, w, lane);
    __syncthreads();

    bf16x8 ah[4], al[4], bh[4], bl[4];
    #pragma unroll
    for (int m = 0; m < 4; ++m) {
      ah[m] = ld_frag(lds[0], wr * 64 + m * 16, lane);
      al[m] = ld_frag(lds[1], wr * 64 + m * 16, lane);
    }
    #pragma unroll
    for (int n = 0; n < 4; ++n) {
      bh[n] = ld_frag(lds[2], wc * 64 + n * 16, lane);
      bl[n] = ld_frag(lds[3], wc * 64 + n * 16, lane);
    }
    #pragma unroll
    for (int m = 0; m < 4; ++m)
      #pragma unroll
      for (int n = 0; n < 4; ++n)
        acc[m][n] = __builtin_amdgcn_mfma_f32_16x16x32_bf16(ah[m], bh[n], acc[m][n], 0, 0, 0);
    #pragma unroll
    for (int m = 0; m < 4; ++m)
      #pragma unroll
      for (int n = 0; n < 4; ++n)
        acc[m][n] = __builtin_amdgcn_mfma_f32_16x16x32_bf16(ah[m], bl[n], acc[m][n], 0, 0, 0);
    #pragma unroll
    for (int m = 0; m < 4; ++m)
      #pragma unroll
      for (int n = 0; n < 4; ++n)
        acc[m][n] = __builtin_amdgcn_mfma_f32_16x16x32_bf16(al[m], bh[n], acc[m][n], 0, 0, 0);
    __syncthreads();
  }

  // epilogue: C/D layout col = lane&15, row = (lane>>4)*4 + r
  const int rbase = (lane >> 4) * 4;
  const int cidx = lane & 15;
  #pragma unroll
  for (int m = 0; m < 4; ++m) {
    int grow0 = bm + wr * 64 + m * 16 + rbase;
    #pragma unroll
    for (int n = 0; n < 4; ++n) {
      int gcol = bn + wc * 64 + n * 16 + cidx;
      if (gcol < N) {
        #pragma unroll
        for (int r = 0; r < 4; ++r) {
          float v = acc[m][n][r];
          if (EPI == 1) {
            v += bias[gcol];
            v = fmaxf(v, 0.f) + log1pf(expf(-fabsf(v)));
          }
          C[(size_t)(grow0 + r) * ldc + gcol] = v;
        }
      }
    }
  }
}

// ---------------------------------------------------------------------------
// Depthwise causal conv (D_CONV=4) + bias + SiLU -> u_c hi/lo bf16 planes.
// ---------------------------------------------------------------------------
__global__ __launch_bounds__(256) void conv_silu(
    const float* __restrict__ xz, const float* __restrict__ w,
    const float* __restrict__ bias, u16* __restrict__ uch,
    u16* __restrict__ ucl) {
  int idx = blockIdx.x * blockDim.x + threadIdx.x; // over BL*DI
  int d  = idx & (DI - 1);
  int bl = idx >> 11;
  int b  = bl >> 11;
  int l  = bl & (Lc - 1);
  float4 wv = *reinterpret_cast<const float4*>(&w[d * 4]);
  float acc = bias[d];
  const float wk[4] = {wv.x, wv.y, wv.z, wv.w};
  #pragma unroll
  for (int k = 0; k < 4; ++k) {
    int ls = l - 3 + k;
    if (ls >= 0) acc = fmaf(xz[((size_t)(b * Lc + ls)) * (2 * DI) + d], wk[k], acc);
  }
  acc = acc * __frcp_rn(1.f + __expf(-acc)); // silu
  u16 h = f2b(acc);
  uch[idx] = h;
  ucl[idx] = f2b(acc - b2f(h));
}

// ---------------------------------------------------------------------------
// Chunked scan, pass A (d-parallel): one thread per (b, d, chunk); all 16
// states in registers. Stores P[s] = exp2(Av2[s] * sum(dt)) and local final
// h[s] at Pa/hA[c][bd*16+s]. Thread bits: d[0:11) b[11] c[12:17).
// ---------------------------------------------------------------------------
__global__ __launch_bounds__(256) void scan_chunk_local(
    const float* __restrict__ delta, const u16* __restrict__ uch,
    const u16* __restrict__ ucl, const float* __restrict__ xdbl,
    const float* __restrict__ A_log, float* __restrict__ Pa,
    float* __restrict__ hA) {
  const int t = blockIdx.x * 256 + threadIdx.x;
  const int d = t & (DI - 1);
  const int b = (t >> 11) & (Bc - 1);
  const int c = t >> 12;
  const int bd = (b << 11) | d;

  float Av2[DS];
  {
    const float4* ap = reinterpret_cast<const float4*>(&A_log[(size_t)d * DS]);
    #pragma unroll
    for (int q = 0; q < 4; ++q) {
      float4 a = ap[q];
      Av2[4*q+0] = -LOG2E * __expf(a.x);
      Av2[4*q+1] = -LOG2E * __expf(a.y);
      Av2[4*q+2] = -LOG2E * __expf(a.z);
      Av2[4*q+3] = -LOG2E * __expf(a.w);
    }
  }
  const size_t rowbase = (size_t)(b * Lc + c * CH);
  const float* dp  = delta + rowbase * DI + d;
  const u16*   uhp = uch   + rowbase * DI + d;
  const u16*   ulp = ucl   + rowbase * DI + d;
  const float4* xp = reinterpret_cast<const float4*>(xdbl + rowbase * NX + DR);

  float h[DS] = {};
  float S = 0.f;
  float dt = dp[0];
  float ut = b2f(uhp[0]) + b2f(ulp[0]);
  float4 B0 = xp[0], B1 = xp[1], B2 = xp[2], B3 = xp[3];

  for (int l = 0; l < CH; ++l) {
    const int ln = (l + 1 < CH) ? l + 1 : l;
    // prefetch next iteration (stream hides under the 16-wide compute)
    float dtn = dp[ln * DI];
    float utn = b2f(uhp[ln * DI]) + b2f(ulp[ln * DI]);
    const float4* xn = xp + ln * (NX / 4);
    float4 B0n = xn[0], B1n = xn[1], B2n = xn[2], B3n = xn[3];

    float Bs[16];
    *reinterpret_cast<float4*>(&Bs[0])  = B0;
    *reinterpret_cast<float4*>(&Bs[4])  = B1;
    *reinterpret_cast<float4*>(&Bs[8])  = B2;
    *reinterpret_cast<float4*>(&Bs[12]) = B3;
    const float dtu = dt * ut;
    S += dt;
    #pragma unroll
    for (int s = 0; s < DS; ++s) {
      float dA = exp2f(dt * Av2[s]);
      h[s] = fmaf(dA, h[s], dtu * Bs[s]);
    }
    dt = dtn; ut = utn; B0 = B0n; B1 = B1n; B2 = B2n; B3 = B3n;
  }

  float4* Pp = reinterpret_cast<float4*>(&Pa[(size_t)c * BDS + (size_t)bd * DS]);
  float4* Hp = reinterpret_cast<float4*>(&hA[(size_t)c * BDS + (size_t)bd * DS]);
  #pragma unroll
  for (int q = 0; q < 4; ++q) {
    float4 pv, hv;
    pv.x = exp2f(Av2[4*q+0] * S); pv.y = exp2f(Av2[4*q+1] * S);
    pv.z = exp2f(Av2[4*q+2] * S); pv.w = exp2f(Av2[4*q+3] * S);
    hv.x = h[4*q+0]; hv.y = h[4*q+1]; hv.z = h[4*q+2]; hv.w = h[4*q+3];
    Pp[q] = pv; Hp[q] = hv;
  }
}

// ---------------------------------------------------------------------------
// Pass B: serial carry across chunks; h0 written in-place over Pa.
// ---------------------------------------------------------------------------
__global__ __launch_bounds__(256) void scan_chunk_carry(
    float* Pa_h0, const float* __restrict__ hA) {
  const int t = blockIdx.x * 256 + threadIdx.x; // over BDS
  float pa[NC], ha[NC];
  #pragma unroll
  for (int c = 0; c < NC; ++c) {
    pa[c] = Pa_h0[(size_t)c * BDS + t];
    ha[c] = hA[(size_t)c * BDS + t];
  }
  float h = 0.f;
  #pragma unroll
  for (int c = 0; c < NC; ++c) {
    Pa_h0[(size_t)c * BDS + t] = h;
    h = fmaf(pa[c], h, ha[c]);
  }
}

// ---------------------------------------------------------------------------
// Pass C (d-parallel): re-run local scan from carry-in h0, y in-register,
// skip + gate, write y hi/lo bf16 over the uc planes. Each element is read
// (prefetch, iter l-1) strictly before written (iter l) by its sole owner
// thread, so the in-place alias is safe.
// ---------------------------------------------------------------------------
__global__ __launch_bounds__(256) void scan_chunk_final(
    const float* __restrict__ delta, const u16* uch, const u16* ucl,
    const float* __restrict__ xdbl, const float* __restrict__ xz,
    const float* __restrict__ A_log, const float* __restrict__ Dv,
    const float* __restrict__ h0, u16* yh, u16* yl) {
  const int t = blockIdx.x * 256 + threadIdx.x;
  const int d = t & (DI - 1);
  const int b = (t >> 11) & (Bc - 1);
  const int c = t >> 12;
  const int bd = (b << 11) | d;

  float Av2[DS];
  {
    const float4* ap = reinterpret_cast<const float4*>(&A_log[(size_t)d * DS]);
    #pragma unroll
    for (int q = 0; q < 4; ++q) {
      float4 a = ap[q];
      Av2[4*q+0] = -LOG2E * __expf(a.x);
      Av2[4*q+1] = -LOG2E * __expf(a.y);
      Av2[4*q+2] = -LOG2E * __expf(a.z);
      Av2[4*q+3] = -LOG2E * __expf(a.w);
    }
  }
  const float Dd = Dv[d];
  float h[DS];
  {
    const float4* hp = reinterpret_cast<const float4*>(&h0[(size_t)c * BDS + (size_t)bd * DS]);
    #pragma unroll
    for (int q = 0; q < 4; ++q) {
      float4 hv = hp[q];
      h[4*q+0] = hv.x; h[4*q+1] = hv.y; h[4*q+2] = hv.z; h[4*q+3] = hv.w;
    }
  }
  const size_t rowbase = (size_t)(b * Lc + c * CH);
  const float* dp  = delta + rowbase * DI + d;
  const u16*   uhp = uch   + rowbase * DI + d;
  const u16*   ulp = ucl   + rowbase * DI + d;
  const float* zp  = xz    + rowbase * (2 * DI) + DI + d;
  const float4* xp = reinterpret_cast<const float4*>(xdbl + rowbase * NX + DR);
  u16* yhp = yh + rowbase * DI + d;
  u16* ylp = yl + rowbase * DI + d;

  float dt = dp[0];
  float ut = b2f(uhp[0]) + b2f(ulp[0]);
  float zt = zp[0];
  float4 B0 = xp[0], B1 = xp[1], B2 = xp[2], B3 = xp[3];
  float4 C0 = xp[4], C1 = xp[5], C2 = xp[6], C3 = xp[7];

  for (int l = 0; l < CH; ++l) {
    const int ln = (l + 1 < CH) ? l + 1 : l;
    float dtn = dp[ln * DI];
    float utn = b2f(uhp[ln * DI]) + b2f(ulp[ln * DI]);
    float ztn = zp[ln * (2 * DI)];
    const float4* xn = xp + ln * (NX / 4);
    float4 B0n = xn[0], B1n = xn[1], B2n = xn[2], B3n = xn[3];
    float4 C0n = xn[4], C1n = xn[5], C2n = xn[6], C3n = xn[7];

    float Bs[16], Cs[16];
    *reinterpret_cast<float4*>(&Bs[0])  = B0;
    *reinterpret_cast<float4*>(&Bs[4])  = B1;
    *reinterpret_cast<float4*>(&Bs[8])  = B2;
    *reinterpret_cast<float4*>(&Bs[12]) = B3;
    *reinterpret_cast<float4*>(&Cs[0])  = C0;
    *reinterpret_cast<float4*>(&Cs[4])  = C1;
    *reinterpret_cast<float4*>(&Cs[8])  = C2;
    *reinterpret_cast<float4*>(&Cs[12]) = C3;
    const float dtu = dt * ut;
    float y0 = 0.f, y1 = 0.f;
    #pragma unroll
    for (int s = 0; s < DS; ++s) {
      float dA = exp2f(dt * Av2[s]);
      h[s] = fmaf(dA, h[s], dtu * Bs[s]);
      if (s & 1) y1 = fmaf(h[s], Cs[s], y1);
      else       y0 = fmaf(h[s], Cs[s], y0);
    }
    float gate = zt * __frcp_rn(1.f + exp2f(-LOG2E * zt));
    float y = (y0 + y1 + Dd * ut) * gate;
    u16 hh = f2b(y);
    yhp[l * DI] = hh;
    ylp[l * DI] = f2b(y - b2f(hh));

    dt = dtn; ut = utn; zt = ztn;
    B0 = B0n; B1 = B1n; B2 = B2n; B3 = B3n;
    C0 = C0n; C1 = C1n; C2 = C2n; C3 = C3n;
  }
}

// ---------------------------------------------------------------------------
extern "C" void kernel_launch(void* const* d_in, const int* in_sizes, int n_in,
                              void* d_out, int out_size, void* d_ws, size_t ws_size,
                              hipStream_t stream) {
  const float* x        = (const float*)d_in[0];
  const float* W_in     = (const float*)d_in[1];
  const float* conv_w   = (const float*)d_in[2];
  const float* conv_b   = (const float*)d_in[3];
  const float* W_xproj  = (const float*)d_in[4];
  const float* W_dtproj = (const float*)d_in[5];
  const float* dt_bias  = (const float*)d_in[6];
  const float* A_log    = (const float*)d_in[7];
  const float* Dv       = (const float*)d_in[8];
  const float* W_out    = (const float*)d_in[9];
  float* out = (float*)d_out;

  char* W = (char*)d_ws;
  size_t off = 0;
  float* xz  = (float*)(W + off);  off += (size_t)BL * 4096 * 4;    // 64 MB
  size_t delta_off = off;
  u16* xh   = (u16*)(W + off);     off += (size_t)BL * DM * 2;      // 8 MB
  u16* xl   = (u16*)(W + off);     off += (size_t)BL * DM * 2;      // 8 MB
  u16* Wih  = (u16*)(W + off);     off += (size_t)(2 * DI) * DM * 2;// 8 MB
  u16* Wil  = (u16*)(W + off);     off += (size_t)(2 * DI) * DM * 2;// 8 MB
  float* delta = (float*)(W + delta_off);  // 32 MB, aliases xh..Wil (dead post in_proj)
  u16* uch  = (u16*)(W + off);     off += (size_t)BL * DI * 2;      // 16 MB
  u16* ucl  = (u16*)(W + off);     off += (size_t)BL * DI * 2;      // 16 MB
  u16* Wxh  = (u16*)(W + off);     off += (size_t)128 * DI * 2;     // 0.5 MB (padded)
  u16* Wxl  = (u16*)(W + off);     off += (size_t)128 * DI * 2;
  float* xdbl = (float*)(W + off); off += (size_t)BL * NX * 4;      // 1.5 MB
  u16* xdh  = (u16*)(W + off);     off += (size_t)BL * NX * 2;
  u16* xdl  = (u16*)(W + off);     off += (size_t)BL * NX * 2;
  u16* Wdh  = (u16*)(W + off);     off += (size_t)DI * DR * 2;
  u16* Wdl  = (u16*)(W + off);     off += (size_t)DI * DR * 2;
  u16* Woh  = (u16*)(W + off);     off += (size_t)DM * DI * 2;      // 4 MB
  u16* Wol  = (u16*)(W + off);     off += (size_t)DM * DI * 2;      // 4 MB
  float* Pa = (float*)(W + off);   off += (size_t)NC * BDS * 4;     // 8 MB
  float* hA = (float*)(W + off);   off += (size_t)NC * BDS * 4;     // 8 MB
  float* h0 = Pa;                  // pass B writes h0 in-place over Pa
  u16* yh = uch;                   // pass C writes y over uc planes (safe)
  u16* yl = ucl;

  // 0) conversions to bf16 hi/lo planes
  cvt_hilo<<<(BL * DM / 4 + 255) / 256, 256, 0, stream>>>(x, xh, xl, BL * DM / 4);
  cvt_hilo<<<(2 * DI * DM / 4 + 255) / 256, 256, 0, stream>>>(W_in, Wih, Wil, 2 * DI * DM / 4);
  cvt_pad_wx<<<(128 * DI / 4) / 256, 256, 0, stream>>>(W_xproj, Wxh, Wxl);
  cvt_hilo<<<(DI * DR / 4 + 255) / 256, 256, 0, stream>>>(W_dtproj, Wdh, Wdl, DI * DR / 4);
  cvt_hilo<<<(DM * DI / 4 + 255) / 256, 256, 0, stream>>>(W_out, Woh, Wol, DM * DI / 4);

  // 1) in_proj: xz = x @ W_in^T   (M=4096, N=4096, K=1024)
  gemm_mfma<0><<<dim3(BL / 128, (2 * DI) / 128), 256, 0, stream>>>(
      xh, xl, Wih, Wil, nullptr, xz, BL, 2 * DI, DM, DM, DM, 2 * DI);

  // 2) depthwise causal conv + SiLU -> uc hi/lo planes
  conv_silu<<<(BL * DI) / 256, 256, 0, stream>>>(xz, conv_w, conv_b, uch, ucl);

  // 3) x_proj: xdbl = u_c @ W_xproj^T  (N=96, padded B planes)
  gemm_mfma<0><<<dim3(BL / 128, 1), 256, 0, stream>>>(
      uch, ucl, Wxh, Wxl, nullptr, xdbl, BL, NX, DI, DI, DI, NX);

  // 3b) xdbl -> hi/lo (dt_proj A operand)
  cvt_hilo<<<(BL * NX / 4 + 255) / 256, 256, 0, stream>>>(xdbl, xdh, xdl, BL * NX / 4);

  // 4) dt_proj + softplus: delta = softplus(xdbl[:, :64] @ W_dtproj^T + bias)
  gemm_mfma<1><<<dim3(BL / 128, DI / 128), 256, 0, stream>>>(
      xdh, xdl, Wdh, Wdl, dt_bias, delta, BL, DI, DR, NX, DR, DI);

  // 5) chunked selective scan (3 passes, d-parallel A/C)
  scan_chunk_local<<<(Bc * DI * NC) / 256, 256, 0, stream>>>(
      delta, uch, ucl, xdbl, A_log, Pa, hA);
  scan_chunk_carry<<<BDS / 256, 256, 0, stream>>>(Pa, hA);
  scan_chunk_final<<<(Bc * DI * NC) / 256, 256, 0, stream>>>(
      delta, uch, ucl, xdbl, xz, A_log, Dv, h0, yh, yl);

  // 6) out_proj: out = y @ W_out^T  (M=4096, N=1024, K=2048)
  gemm_mfma<0><<<dim3(BL / 128, DM / 128), 256, 0, stream>>>(
      yh, yl, Woh, Wol, nullptr, out, BL, DM, DI, DI, DI, DM);
}

// Round 6
// 468.757 us; speedup vs baseline: 7.2946x; 1.1793x over previous
//
#include <hip/hip_runtime.h>
#include <cstdint>
#include <cstddef>

constexpr int Bc = 2, Lc = 2048, DM = 1024, DI = 2048, DS = 16, DR = 64, NX = 96;
constexpr int BL = Bc * Lc;          // 4096
constexpr int NC = 32, CH = 64;      // chunks / chunk length
constexpr int BDS = Bc * DI * DS;    // 65536
constexpr float LOG2E = 1.44269504f;

typedef __attribute__((ext_vector_type(8))) short bf16x8;
typedef __attribute__((ext_vector_type(4))) float f32x4;
typedef unsigned short u16;

__device__ __forceinline__ u16 f2b(float f) {          // fp32 -> bf16 (RNE)
  uint32_t u = __float_as_uint(f);
  return (u16)((u + 0x7FFFu + ((u >> 16) & 1u)) >> 16);
}
__device__ __forceinline__ float b2f(u16 h) {
  return __uint_as_float(((uint32_t)h) << 16);
}

// ---------------------------------------------------------------------------
// fp32 -> (hi, lo) bf16 planes, vectorized float4.
// ---------------------------------------------------------------------------
__global__ __launch_bounds__(256) void cvt_hilo(
    const float* __restrict__ in, u16* __restrict__ hi, u16* __restrict__ lo,
    int n4) {
  int i = blockIdx.x * 256 + threadIdx.x;
  if (i >= n4) return;
  float4 v = reinterpret_cast<const float4*>(in)[i];
  ushort4 H, L;
  H.x = f2b(v.x); L.x = f2b(v.x - b2f(H.x));
  H.y = f2b(v.y); L.y = f2b(v.y - b2f(H.y));
  H.z = f2b(v.z); L.z = f2b(v.z - b2f(H.z));
  H.w = f2b(v.w); L.w = f2b(v.w - b2f(H.w));
  reinterpret_cast<ushort4*>(hi)[i] = H;
  reinterpret_cast<ushort4*>(lo)[i] = L;
}

// W_xproj [96][2048] -> padded [128][2048] hi/lo planes (rows >=96 zero).
__global__ __launch_bounds__(256) void cvt_pad_wx(
    const float* __restrict__ w, u16* __restrict__ hi, u16* __restrict__ lo) {
  int i = blockIdx.x * 256 + threadIdx.x;      // over 128*2048/4 = 65536
  int f = i * 4;
  int row = f >> 11;
  ushort4 H, L;
  H.x = H.y = H.z = H.w = 0; L = H;
  if (row < 96) {
    float4 v = *reinterpret_cast<const float4*>(&w[f]);
    H.x = f2b(v.x); L.x = f2b(v.x - b2f(H.x));
    H.y = f2b(v.y); L.y = f2b(v.y - b2f(H.y));
    H.z = f2b(v.z); L.z = f2b(v.z - b2f(H.z));
    H.w = f2b(v.w); L.w = f2b(v.w - b2f(H.w));
  }
  reinterpret_cast<ushort4*>(hi)[i] = H;
  reinterpret_cast<ushort4*>(lo)[i] = L;
}

// ---------------------------------------------------------------------------
// Split-bf16 MFMA GEMM: C[M,N](fp32) = A[M,K] @ B[N,K]^T via hi/lo planes.
// 128x128 tile, BK=32, 4 waves (2x2), 16x16x32 bf16 MFMA, 3 passes
// (hi*hi + hi*lo + lo*hi). T3 2-phase pipeline: double-buffered LDS, stage
// t+1 issued BEFORE tile t's ds_read+MFMA so the end-of-iter vmcnt(0) drain
// overlaps ~450cy of compute. setprio(1) around the MFMA cluster (T5).
// ---------------------------------------------------------------------------
__device__ __forceinline__ void stage_tile(
    const u16* __restrict__ g, u16* lds, int row0, int ld, int k0,
    int w, int lane) {
  #pragma unroll
  for (int i = 0; i < 2; ++i) {
    const int base = w * 1024 + i * 4096;          // wave-uniform byte base
    const int o = base + lane * 16;                // this lane's byte slot
    const int row = o >> 6;                        // 64B per row (32 bf16)
    const int sl = ((o >> 4) & 3) ^ ((row >> 1) & 3);  // inverse swizzle
    const u16* src = g + (size_t)(row0 + row) * ld + (k0 + sl * 8);
    __builtin_amdgcn_global_load_lds(
        (const __attribute__((address_space(1))) unsigned int*)src,
        (__attribute__((address_space(3))) unsigned int*)(lds + base / 2),
        16, 0, 0);
  }
}

__device__ __forceinline__ void stage4(
    const u16* __restrict__ Ah, const u16* __restrict__ Al,
    const u16* __restrict__ Bh, const u16* __restrict__ Bl,
    u16* buf /* [4][4096] */, int bm, int bn, int lda, int ldb,
    int k0, int w, int lane) {
  stage_tile(Ah, buf + 0 * 4096, bm, lda, k0, w, lane);
  stage_tile(Al, buf + 1 * 4096, bm, lda, k0, w, lane);
  stage_tile(Bh, buf + 2 * 4096, bn, ldb, k0, w, lane);
  stage_tile(Bl, buf + 3 * 4096, bn, ldb, k0, w, lane);
}

__device__ __forceinline__ bf16x8 ld_frag(const u16* plane, int rowbase, int lane) {
  const int row = rowbase + (lane & 15);
  const int kb = (lane >> 4) ^ ((row >> 1) & 3);   // swizzled 16B slot
  return *reinterpret_cast<const bf16x8*>(
      reinterpret_cast<const char*>(plane) + row * 64 + kb * 16);
}

template<int EPI>
__global__ __launch_bounds__(256) void gemm_mfma(
    const u16* __restrict__ Ah, const u16* __restrict__ Al,
    const u16* __restrict__ Bh, const u16* __restrict__ Bl,
    const float* __restrict__ bias, float* __restrict__ C,
    int M, int N, int K, int lda, int ldb, int ldc) {
  __shared__ __align__(16) u16 lds[2][4][4096];    // double-buffered, 64 KB
  const int tid = threadIdx.x;
  const int lane = tid & 63, w = tid >> 6;
  const int wr = w >> 1, wc = w & 1;
  const int bm = blockIdx.x * 128, bn = blockIdx.y * 128;

  f32x4 acc[4][4] = {};

  const int nt = K / 32;
  // prologue: stage tile 0, wait, barrier
  stage4(Ah, Al, Bh, Bl, &lds[0][0][0], bm, bn, lda, ldb, 0, w, lane);
  __syncthreads();

  int cur = 0;
  for (int t = 0; t < nt; ++t) {
    // issue next tile's async loads FIRST (hide latency under compute)
    if (t + 1 < nt)
      stage4(Ah, Al, Bh, Bl, &lds[cur ^ 1][0][0], bm, bn, lda, ldb,
             (t + 1) * 32, w, lane);

    const u16* Lb = &lds[cur][0][0];
    bf16x8 ah[4], al[4], bh[4], bl[4];
    #pragma unroll
    for (int m = 0; m < 4; ++m) {
      ah[m] = ld_frag(Lb + 0 * 4096, wr * 64 + m * 16, lane);
      al[m] = ld_frag(Lb + 1 * 4096, wr * 64 + m * 16, lane);
    }
    #pragma unroll
    for (int n = 0; n < 4; ++n) {
      bh[n] = ld_frag(Lb + 2 * 4096, wc * 64 + n * 16, lane);
      bl[n] = ld_frag(Lb + 3 * 4096, wc * 64 + n * 16, lane);
    }
    __builtin_amdgcn_s_setprio(1);
    #pragma unroll
    for (int m = 0; m < 4; ++m)
      #pragma unroll
      for (int n = 0; n < 4; ++n)
        acc[m][n] = __builtin_amdgcn_mfma_f32_16x16x32_bf16(ah[m], bh[n], acc[m][n], 0, 0, 0);
    #pragma unroll
    for (int m = 0; m < 4; ++m)
      #pragma unroll
      for (int n = 0; n < 4; ++n)
        acc[m][n] = __builtin_amdgcn_mfma_f32_16x16x32_bf16(ah[m], bl[n], acc[m][n], 0, 0, 0);
    #pragma unroll
    for (int m = 0; m < 4; ++m)
      #pragma unroll
      for (int n = 0; n < 4; ++n)
        acc[m][n] = __builtin_amdgcn_mfma_f32_16x16x32_bf16(al[m], bh[n], acc[m][n], 0, 0, 0);
    __builtin_amdgcn_s_setprio(0);
    // drains vmcnt(0): next tile's loads have had the whole MFMA phase
    __syncthreads();
    cur ^= 1;
  }

  // epilogue: C/D layout col = lane&15, row = (lane>>4)*4 + r
  const int rbase = (lane >> 4) * 4;
  const int cidx = lane & 15;
  #pragma unroll
  for (int m = 0; m < 4; ++m) {
    int grow0 = bm + wr * 64 + m * 16 + rbase;
    #pragma unroll
    for (int n = 0; n < 4; ++n) {
      int gcol = bn + wc * 64 + n * 16 + cidx;
      if (gcol < N) {
        #pragma unroll
        for (int r = 0; r < 4; ++r) {
          float v = acc[m][n][r];
          if (EPI == 1) {
            v += bias[gcol];
            v = fmaxf(v, 0.f) + log1pf(expf(-fabsf(v)));
          }
          C[(size_t)(grow0 + r) * ldc + gcol] = v;
        }
      }
    }
  }
}

// ---------------------------------------------------------------------------
// Depthwise causal conv (D_CONV=4) + bias + SiLU -> u_c hi/lo bf16 planes.
// ---------------------------------------------------------------------------
__global__ __launch_bounds__(256) void conv_silu(
    const float* __restrict__ xz, const float* __restrict__ w,
    const float* __restrict__ bias, u16* __restrict__ uch,
    u16* __restrict__ ucl) {
  int idx = blockIdx.x * blockDim.x + threadIdx.x; // over BL*DI
  int d  = idx & (DI - 1);
  int bl = idx >> 11;
  int b  = bl >> 11;
  int l  = bl & (Lc - 1);
  float4 wv = *reinterpret_cast<const float4*>(&w[d * 4]);
  float acc = bias[d];
  const float wk[4] = {wv.x, wv.y, wv.z, wv.w};
  #pragma unroll
  for (int k = 0; k < 4; ++k) {
    int ls = l - 3 + k;
    if (ls >= 0) acc = fmaf(xz[((size_t)(b * Lc + ls)) * (2 * DI) + d], wk[k], acc);
  }
  acc = acc * __frcp_rn(1.f + __expf(-acc)); // silu
  u16 h = f2b(acc);
  uch[idx] = h;
  ucl[idx] = f2b(acc - b2f(h));
}

// ---------------------------------------------------------------------------
// Chunked scan, pass A (d-parallel): one thread per (b, d, chunk); all 16
// states in registers. Stores P[s] = exp2(Av2[s] * sum(dt)) and local final
// h[s] at Pa/hA[c][bd*16+s]. Thread bits: d[0:11) b[11] c[12:17).
// ---------------------------------------------------------------------------
__global__ __launch_bounds__(256) void scan_chunk_local(
    const float* __restrict__ delta, const u16* __restrict__ uch,
    const u16* __restrict__ ucl, const float* __restrict__ xdbl,
    const float* __restrict__ A_log, float* __restrict__ Pa,
    float* __restrict__ hA) {
  const int t = blockIdx.x * 256 + threadIdx.x;
  const int d = t & (DI - 1);
  const int b = (t >> 11) & (Bc - 1);
  const int c = t >> 12;
  const int bd = (b << 11) | d;

  float Av2[DS];
  {
    const float4* ap = reinterpret_cast<const float4*>(&A_log[(size_t)d * DS]);
    #pragma unroll
    for (int q = 0; q < 4; ++q) {
      float4 a = ap[q];
      Av2[4*q+0] = -LOG2E * __expf(a.x);
      Av2[4*q+1] = -LOG2E * __expf(a.y);
      Av2[4*q+2] = -LOG2E * __expf(a.z);
      Av2[4*q+3] = -LOG2E * __expf(a.w);
    }
  }
  const size_t rowbase = (size_t)(b * Lc + c * CH);
  const float* dp  = delta + rowbase * DI + d;
  const u16*   uhp = uch   + rowbase * DI + d;
  const u16*   ulp = ucl   + rowbase * DI + d;
  const float4* xp = reinterpret_cast<const float4*>(xdbl + rowbase * NX + DR);

  float h[DS] = {};
  float S = 0.f;
  float dt = dp[0];
  float ut = b2f(uhp[0]) + b2f(ulp[0]);
  float4 B0 = xp[0], B1 = xp[1], B2 = xp[2], B3 = xp[3];

  for (int l = 0; l < CH; ++l) {
    const int ln = (l + 1 < CH) ? l + 1 : l;
    float dtn = dp[ln * DI];
    float utn = b2f(uhp[ln * DI]) + b2f(ulp[ln * DI]);
    const float4* xn = xp + ln * (NX / 4);
    float4 B0n = xn[0], B1n = xn[1], B2n = xn[2], B3n = xn[3];

    float Bs[16];
    *reinterpret_cast<float4*>(&Bs[0])  = B0;
    *reinterpret_cast<float4*>(&Bs[4])  = B1;
    *reinterpret_cast<float4*>(&Bs[8])  = B2;
    *reinterpret_cast<float4*>(&Bs[12]) = B3;
    const float dtu = dt * ut;
    S += dt;
    #pragma unroll
    for (int s = 0; s < DS; ++s) {
      float dA = exp2f(dt * Av2[s]);
      h[s] = fmaf(dA, h[s], dtu * Bs[s]);
    }
    dt = dtn; ut = utn; B0 = B0n; B1 = B1n; B2 = B2n; B3 = B3n;
  }

  float4* Pp = reinterpret_cast<float4*>(&Pa[(size_t)c * BDS + (size_t)bd * DS]);
  float4* Hp = reinterpret_cast<float4*>(&hA[(size_t)c * BDS + (size_t)bd * DS]);
  #pragma unroll
  for (int q = 0; q < 4; ++q) {
    float4 pv, hv;
    pv.x = exp2f(Av2[4*q+0] * S); pv.y = exp2f(Av2[4*q+1] * S);
    pv.z = exp2f(Av2[4*q+2] * S); pv.w = exp2f(Av2[4*q+3] * S);
    hv.x = h[4*q+0]; hv.y = h[4*q+1]; hv.z = h[4*q+2]; hv.w = h[4*q+3];
    Pp[q] = pv; Hp[q] = hv;
  }
}

// ---------------------------------------------------------------------------
// Pass B: serial carry across chunks; h0 written in-place over Pa.
// ---------------------------------------------------------------------------
__global__ __launch_bounds__(256) void scan_chunk_carry(
    float* Pa_h0, const float* __restrict__ hA) {
  const int t = blockIdx.x * 256 + threadIdx.x; // over BDS
  float pa[NC], ha[NC];
  #pragma unroll
  for (int c = 0; c < NC; ++c) {
    pa[c] = Pa_h0[(size_t)c * BDS + t];
    ha[c] = hA[(size_t)c * BDS + t];
  }
  float h = 0.f;
  #pragma unroll
  for (int c = 0; c < NC; ++c) {
    Pa_h0[(size_t)c * BDS + t] = h;
    h = fmaf(pa[c], h, ha[c]);
  }
}

// ---------------------------------------------------------------------------
// Pass C (d-parallel): re-run local scan from carry-in h0, y in-register,
// skip + gate, write y hi/lo bf16 over the uc planes (element read strictly
// before written by its sole owner thread).
// ---------------------------------------------------------------------------
__global__ __launch_bounds__(256) void scan_chunk_final(
    const float* __restrict__ delta, const u16* uch, const u16* ucl,
    const float* __restrict__ xdbl, const float* __restrict__ xz,
    const float* __restrict__ A_log, const float* __restrict__ Dv,
    const float* __restrict__ h0, u16* yh, u16* yl) {
  const int t = blockIdx.x * 256 + threadIdx.x;
  const int d = t & (DI - 1);
  const int b = (t >> 11) & (Bc - 1);
  const int c = t >> 12;
  const int bd = (b << 11) | d;

  float Av2[DS];
  {
    const float4* ap = reinterpret_cast<const float4*>(&A_log[(size_t)d * DS]);
    #pragma unroll
    for (int q = 0; q < 4; ++q) {
      float4 a = ap[q];
      Av2[4*q+0] = -LOG2E * __expf(a.x);
      Av2[4*q+1] = -LOG2E * __expf(a.y);
      Av2[4*q+2] = -LOG2E * __expf(a.z);
      Av2[4*q+3] = -LOG2E * __expf(a.w);
    }
  }
  const float Dd = Dv[d];
  float h[DS];
  {
    const float4* hp = reinterpret_cast<const float4*>(&h0[(size_t)c * BDS + (size_t)bd * DS]);
    #pragma unroll
    for (int q = 0; q < 4; ++q) {
      float4 hv = hp[q];
      h[4*q+0] = hv.x; h[4*q+1] = hv.y; h[4*q+2] = hv.z; h[4*q+3] = hv.w;
    }
  }
  const size_t rowbase = (size_t)(b * Lc + c * CH);
  const float* dp  = delta + rowbase * DI + d;
  const u16*   uhp = uch   + rowbase * DI + d;
  const u16*   ulp = ucl   + rowbase * DI + d;
  const float* zp  = xz    + rowbase * (2 * DI) + DI + d;
  const float4* xp = reinterpret_cast<const float4*>(xdbl + rowbase * NX + DR);
  u16* yhp = yh + rowbase * DI + d;
  u16* ylp = yl + rowbase * DI + d;

  float dt = dp[0];
  float ut = b2f(uhp[0]) + b2f(ulp[0]);
  float zt = zp[0];
  float4 B0 = xp[0], B1 = xp[1], B2 = xp[2], B3 = xp[3];
  float4 C0 = xp[4], C1 = xp[5], C2 = xp[6], C3 = xp[7];

  for (int l = 0; l < CH; ++l) {
    const int ln = (l + 1 < CH) ? l + 1 : l;
    float dtn = dp[ln * DI];
    float utn = b2f(uhp[ln * DI]) + b2f(ulp[ln * DI]);
    float ztn = zp[ln * (2 * DI)];
    const float4* xn = xp + ln * (NX / 4);
    float4 B0n = xn[0], B1n = xn[1], B2n = xn[2], B3n = xn[3];
    float4 C0n = xn[4], C1n = xn[5], C2n = xn[6], C3n = xn[7];

    float Bs[16], Cs[16];
    *reinterpret_cast<float4*>(&Bs[0])  = B0;
    *reinterpret_cast<float4*>(&Bs[4])  = B1;
    *reinterpret_cast<float4*>(&Bs[8])  = B2;
    *reinterpret_cast<float4*>(&Bs[12]) = B3;
    *reinterpret_cast<float4*>(&Cs[0])  = C0;
    *reinterpret_cast<float4*>(&Cs[4])  = C1;
    *reinterpret_cast<float4*>(&Cs[8])  = C2;
    *reinterpret_cast<float4*>(&Cs[12]) = C3;
    const float dtu = dt * ut;
    float y0 = 0.f, y1 = 0.f;
    #pragma unroll
    for (int s = 0; s < DS; ++s) {
      float dA = exp2f(dt * Av2[s]);
      h[s] = fmaf(dA, h[s], dtu * Bs[s]);
      if (s & 1) y1 = fmaf(h[s], Cs[s], y1);
      else       y0 = fmaf(h[s], Cs[s], y0);
    }
    float gate = zt * __frcp_rn(1.f + exp2f(-LOG2E * zt));
    float y = (y0 + y1 + Dd * ut) * gate;
    u16 hh = f2b(y);
    yhp[l * DI] = hh;
    ylp[l * DI] = f2b(y - b2f(hh));

    dt = dtn; ut = utn; zt = ztn;
    B0 = B0n; B1 = B1n; B2 = B2n; B3 = B3n;
    C0 = C0n; C1 = C1n; C2 = C2n; C3 = C3n;
  }
}

// ---------------------------------------------------------------------------
extern "C" void kernel_launch(void* const* d_in, const int* in_sizes, int n_in,
                              void* d_out, int out_size, void* d_ws, size_t ws_size,
                              hipStream_t stream) {
  const float* x        = (const float*)d_in[0];
  const float* W_in     = (const float*)d_in[1];
  const float* conv_w   = (const float*)d_in[2];
  const float* conv_b   = (const float*)d_in[3];
  const float* W_xproj  = (const float*)d_in[4];
  const float* W_dtproj = (const float*)d_in[5];
  const float* dt_bias  = (const float*)d_in[6];
  const float* A_log    = (const float*)d_in[7];
  const float* Dv       = (const float*)d_in[8];
  const float* W_out    = (const float*)d_in[9];
  float* out = (float*)d_out;

  char* W = (char*)d_ws;
  size_t off = 0;
  float* xz  = (float*)(W + off);  off += (size_t)BL * 4096 * 4;    // 64 MB
  size_t delta_off = off;
  u16* xh   = (u16*)(W + off);     off += (size_t)BL * DM * 2;      // 8 MB
  u16* xl   = (u16*)(W + off);     off += (size_t)BL * DM * 2;      // 8 MB
  u16* Wih  = (u16*)(W + off);     off += (size_t)(2 * DI) * DM * 2;// 8 MB
  u16* Wil  = (u16*)(W + off);     off += (size_t)(2 * DI) * DM * 2;// 8 MB
  float* delta = (float*)(W + delta_off);  // 32 MB, aliases xh..Wil (dead post in_proj)
  u16* uch  = (u16*)(W + off);     off += (size_t)BL * DI * 2;      // 16 MB
  u16* ucl  = (u16*)(W + off);     off += (size_t)BL * DI * 2;      // 16 MB
  u16* Wxh  = (u16*)(W + off);     off += (size_t)128 * DI * 2;     // 0.5 MB (padded)
  u16* Wxl  = (u16*)(W + off);     off += (size_t)128 * DI * 2;
  float* xdbl = (float*)(W + off); off += (size_t)BL * NX * 4;      // 1.5 MB
  u16* xdh  = (u16*)(W + off);     off += (size_t)BL * NX * 2;
  u16* xdl  = (u16*)(W + off);     off += (size_t)BL * NX * 2;
  u16* Wdh  = (u16*)(W + off);     off += (size_t)DI * DR * 2;
  u16* Wdl  = (u16*)(W + off);     off += (size_t)DI * DR * 2;
  u16* Woh  = (u16*)(W + off);     off += (size_t)DM * DI * 2;      // 4 MB
  u16* Wol  = (u16*)(W + off);     off += (size_t)DM * DI * 2;      // 4 MB
  float* Pa = (float*)(W + off);   off += (size_t)NC * BDS * 4;     // 8 MB
  float* hA = (float*)(W + off);   off += (size_t)NC * BDS * 4;     // 8 MB
  float* h0 = Pa;                  // pass B writes h0 in-place over Pa
  u16* yh = uch;                   // pass C writes y over uc planes (safe)
  u16* yl = ucl;

  // 0) conversions to bf16 hi/lo planes
  cvt_hilo<<<(BL * DM / 4 + 255) / 256, 256, 0, stream>>>(x, xh, xl, BL * DM / 4);
  cvt_hilo<<<(2 * DI * DM / 4 + 255) / 256, 256, 0, stream>>>(W_in, Wih, Wil, 2 * DI * DM / 4);
  cvt_pad_wx<<<(128 * DI / 4) / 256, 256, 0, stream>>>(W_xproj, Wxh, Wxl);
  cvt_hilo<<<(DI * DR / 4 + 255) / 256, 256, 0, stream>>>(W_dtproj, Wdh, Wdl, DI * DR / 4);
  cvt_hilo<<<(DM * DI / 4 + 255) / 256, 256, 0, stream>>>(W_out, Woh, Wol, DM * DI / 4);

  // 1) in_proj: xz = x @ W_in^T   (M=4096, N=4096, K=1024)
  gemm_mfma<0><<<dim3(BL / 128, (2 * DI) / 128), 256, 0, stream>>>(
      xh, xl, Wih, Wil, nullptr, xz, BL, 2 * DI, DM, DM, DM, 2 * DI);

  // 2) depthwise causal conv + SiLU -> uc hi/lo planes
  conv_silu<<<(BL * DI) / 256, 256, 0, stream>>>(xz, conv_w, conv_b, uch, ucl);

  // 3) x_proj: xdbl = u_c @ W_xproj^T  (N=96, padded B planes)
  gemm_mfma<0><<<dim3(BL / 128, 1), 256, 0, stream>>>(
      uch, ucl, Wxh, Wxl, nullptr, xdbl, BL, NX, DI, DI, DI, NX);

  // 3b) xdbl -> hi/lo (dt_proj A operand)
  cvt_hilo<<<(BL * NX / 4 + 255) / 256, 256, 0, stream>>>(xdbl, xdh, xdl, BL * NX / 4);

  // 4) dt_proj + softplus: delta = softplus(xdbl[:, :64] @ W_dtproj^T + bias)
  gemm_mfma<1><<<dim3(BL / 128, DI / 128), 256, 0, stream>>>(
      xdh, xdl, Wdh, Wdl, dt_bias, delta, BL, DI, DR, NX, DR, DI);

  // 5) chunked selective scan (3 passes, d-parallel A/C)
  scan_chunk_local<<<(Bc * DI * NC) / 256, 256, 0, stream>>>(
      delta, uch, ucl, xdbl, A_log, Pa, hA);
  scan_chunk_carry<<<BDS / 256, 256, 0, stream>>>(Pa, hA);
  scan_chunk_final<<<(Bc * DI * NC) / 256, 256, 0, stream>>>(
      delta, uch, ucl, xdbl, xz, A_log, Dv, h0, yh, yl);

  // 6) out_proj: out = y @ W_out^T  (M=4096, N=1024, K=2048)
  gemm_mfma<0><<<dim3(BL / 128, DM / 128), 256, 0, stream>>>(
      yh, yl, Woh, Wol, nullptr, out, BL, DM, DI, DI, DI, DM);
}

// Round 7
// 437.605 us; speedup vs baseline: 7.8139x; 1.0712x over previous
//
#include <hip/hip_runtime.h>
#include <cstdint>
#include <cstddef>

constexpr int Bc = 2, Lc = 2048, DM = 1024, DI = 2048, DS = 16, DR = 64, NX = 96;
constexpr int BL = Bc * Lc;          // 4096
constexpr int NC = 32, CH = 64;      // scan chunks / chunk length
constexpr int BDS = Bc * DI * DS;    // 65536
constexpr int NSK = 8;               // x_proj split-K factor
constexpr float LOG2E = 1.44269504f;

typedef __attribute__((ext_vector_type(8))) short bf16x8;
typedef __attribute__((ext_vector_type(4))) float f32x4;
typedef unsigned short u16;

__device__ __forceinline__ u16 f2b(float f) {          // fp32 -> bf16 (RNE)
  uint32_t u = __float_as_uint(f);
  return (u16)((u + 0x7FFFu + ((u >> 16) & 1u)) >> 16);
}
__device__ __forceinline__ float b2f(u16 h) {
  return __uint_as_float(((uint32_t)h) << 16);
}

// ---------------------------------------------------------------------------
// fp32 -> (hi, lo) bf16 planes, vectorized float4.
// ---------------------------------------------------------------------------
__global__ __launch_bounds__(256) void cvt_hilo(
    const float* __restrict__ in, u16* __restrict__ hi, u16* __restrict__ lo,
    int n4) {
  int i = blockIdx.x * 256 + threadIdx.x;
  if (i >= n4) return;
  float4 v = reinterpret_cast<const float4*>(in)[i];
  ushort4 H, L;
  H.x = f2b(v.x); L.x = f2b(v.x - b2f(H.x));
  H.y = f2b(v.y); L.y = f2b(v.y - b2f(H.y));
  H.z = f2b(v.z); L.z = f2b(v.z - b2f(H.z));
  H.w = f2b(v.w); L.w = f2b(v.w - b2f(H.w));
  reinterpret_cast<ushort4*>(hi)[i] = H;
  reinterpret_cast<ushort4*>(lo)[i] = L;
}

// W_xproj [96][2048] -> padded [128][2048] hi/lo planes (rows >=96 zero).
__global__ __launch_bounds__(256) void cvt_pad_wx(
    const float* __restrict__ w, u16* __restrict__ hi, u16* __restrict__ lo) {
  int i = blockIdx.x * 256 + threadIdx.x;      // over 128*2048/4 = 65536
  int f = i * 4;
  int row = f >> 11;
  ushort4 H, L;
  H.x = H.y = H.z = H.w = 0; L = H;
  if (row < 96) {
    float4 v = *reinterpret_cast<const float4*>(&w[f]);
    H.x = f2b(v.x); L.x = f2b(v.x - b2f(H.x));
    H.y = f2b(v.y); L.y = f2b(v.y - b2f(H.y));
    H.z = f2b(v.z); L.z = f2b(v.z - b2f(H.z));
    H.w = f2b(v.w); L.w = f2b(v.w - b2f(H.w));
  }
  reinterpret_cast<ushort4*>(hi)[i] = H;
  reinterpret_cast<ushort4*>(lo)[i] = L;
}

// ---------------------------------------------------------------------------
// Split-bf16 MFMA GEMM: C[M,N](fp32) = A[M,K] @ B[N,K]^T via hi/lo planes.
// 128x128 tile, BK=64, 8 waves (4x2), 512 threads, 16x16x32 bf16 MFMA,
// 3 passes (hh + hl + lh). Double-buffered 128 KB LDS, stage-next-then-
// compute-then-syncthreads (structure proven in r6; BK=64 doubles the
// stage->drain distance to hide HBM-miss latency). XOR swizzle
// slot ^= row&7 via pre-swizzled global source + swizzled ds_read.
// Optional split-K over blockIdx.z (partials written at C + z*cSplitStride).
// ---------------------------------------------------------------------------
__device__ __forceinline__ void stage_tile(
    const u16* __restrict__ g, u16* lds, int row0, int ld, int k0,
    int w, int lane) {
  #pragma unroll
  for (int i = 0; i < 2; ++i) {
    const int base = w * 1024 + i * 8192;          // wave-uniform byte base
    const int o = base + lane * 16;                // this lane's byte slot
    const int row = o >> 7;                        // 128B per row (64 bf16)
    const int sl = ((o >> 4) & 7) ^ (row & 7);     // inverse swizzle
    const u16* src = g + (size_t)(row0 + row) * ld + (k0 + sl * 8);
    __builtin_amdgcn_global_load_lds(
        (const __attribute__((address_space(1))) unsigned int*)src,
        (__attribute__((address_space(3))) unsigned int*)(lds + base / 2),
        16, 0, 0);
  }
}

__device__ __forceinline__ void stage4(
    const u16* __restrict__ Ah, const u16* __restrict__ Al,
    const u16* __restrict__ Bh, const u16* __restrict__ Bl,
    u16* buf /* [4][8192] */, int bm, int bn, int lda, int ldb,
    int k0, int w, int lane) {
  stage_tile(Ah, buf + 0 * 8192, bm, lda, k0, w, lane);
  stage_tile(Al, buf + 1 * 8192, bm, lda, k0, w, lane);
  stage_tile(Bh, buf + 2 * 8192, bn, ldb, k0, w, lane);
  stage_tile(Bl, buf + 3 * 8192, bn, ldb, k0, w, lane);
}

__device__ __forceinline__ bf16x8 ld_frag(const u16* plane, int rowbase,
                                          int kk, int lane) {
  const int row = rowbase + (lane & 15);
  const int kb = ((kk << 2) | (lane >> 4)) ^ (row & 7);  // swizzled 16B slot
  return *reinterpret_cast<const bf16x8*>(
      reinterpret_cast<const char*>(plane) + row * 128 + kb * 16);
}

template<int EPI>
__global__ __launch_bounds__(512) void gemm_mfma(
    const u16* __restrict__ Ah, const u16* __restrict__ Al,
    const u16* __restrict__ Bh, const u16* __restrict__ Bl,
    const float* __restrict__ bias, float* __restrict__ C,
    int M, int N, int kEff, int lda, int ldb, int ldc,
    size_t cSplitStride) {
  __shared__ __align__(16) u16 lds[2][4][8192];    // 128 KB, double-buffered
  const int tid = threadIdx.x;
  const int lane = tid & 63, w = tid >> 6;         // 8 waves
  const int wr = w >> 1, wc = w & 1;               // 4x2 wave grid
  const int bm = blockIdx.x * 128, bn = blockIdx.y * 128;
  const int sk = blockIdx.z;
  Ah += (size_t)sk * kEff; Al += (size_t)sk * kEff;
  Bh += (size_t)sk * kEff; Bl += (size_t)sk * kEff;
  C  += (size_t)sk * cSplitStride;

  f32x4 acc[2][4] = {};
  const int nt = kEff >> 6;

  stage4(Ah, Al, Bh, Bl, &lds[0][0][0], bm, bn, lda, ldb, 0, w, lane);
  __syncthreads();

  int cur = 0;
  for (int t = 0; t < nt; ++t) {
    if (t + 1 < nt)
      stage4(Ah, Al, Bh, Bl, &lds[cur ^ 1][0][0], bm, bn, lda, ldb,
             (t + 1) * 64, w, lane);

    const u16* Lb = &lds[cur][0][0];
    #pragma unroll
    for (int kk = 0; kk < 2; ++kk) {
      bf16x8 ah[2], al[2], bh[4], bl[4];
      #pragma unroll
      for (int m = 0; m < 2; ++m) {
        ah[m] = ld_frag(Lb + 0 * 8192, wr * 32 + m * 16, kk, lane);
        al[m] = ld_frag(Lb + 1 * 8192, wr * 32 + m * 16, kk, lane);
      }
      #pragma unroll
      for (int n = 0; n < 4; ++n) {
        bh[n] = ld_frag(Lb + 2 * 8192, wc * 64 + n * 16, kk, lane);
        bl[n] = ld_frag(Lb + 3 * 8192, wc * 64 + n * 16, kk, lane);
      }
      __builtin_amdgcn_s_setprio(1);
      #pragma unroll
      for (int m = 0; m < 2; ++m)
        #pragma unroll
        for (int n = 0; n < 4; ++n)
          acc[m][n] = __builtin_amdgcn_mfma_f32_16x16x32_bf16(ah[m], bh[n], acc[m][n], 0, 0, 0);
      #pragma unroll
      for (int m = 0; m < 2; ++m)
        #pragma unroll
        for (int n = 0; n < 4; ++n)
          acc[m][n] = __builtin_amdgcn_mfma_f32_16x16x32_bf16(ah[m], bl[n], acc[m][n], 0, 0, 0);
      #pragma unroll
      for (int m = 0; m < 2; ++m)
        #pragma unroll
        for (int n = 0; n < 4; ++n)
          acc[m][n] = __builtin_amdgcn_mfma_f32_16x16x32_bf16(al[m], bh[n], acc[m][n], 0, 0, 0);
      __builtin_amdgcn_s_setprio(0);
    }
    __syncthreads();
    cur ^= 1;
  }

  // epilogue: C/D layout col = lane&15, row = (lane>>4)*4 + r
  const int rbase = (lane >> 4) * 4;
  const int cidx = lane & 15;
  #pragma unroll
  for (int m = 0; m < 2; ++m) {
    int grow0 = bm + wr * 32 + m * 16 + rbase;
    #pragma unroll
    for (int n = 0; n < 4; ++n) {
      int gcol = bn + wc * 64 + n * 16 + cidx;
      if (gcol < N) {
        #pragma unroll
        for (int r = 0; r < 4; ++r) {
          float v = acc[m][n][r];
          if (EPI == 1) {
            v += bias[gcol];
            v = fmaxf(v, 0.f) + log1pf(expf(-fabsf(v)));
          }
          C[(size_t)(grow0 + r) * ldc + gcol] = v;
        }
      }
    }
  }
}

// ---------------------------------------------------------------------------
// x_proj split-K reduce: sum NSK partials -> xdbl fp32 + hi/lo planes.
// ---------------------------------------------------------------------------
__global__ __launch_bounds__(256) void xproj_reduce(
    const float* __restrict__ pbuf, float* __restrict__ xdbl,
    u16* __restrict__ xdh, u16* __restrict__ xdl) {
  int i = blockIdx.x * 256 + threadIdx.x;          // over BL*NX/4
  const float4* p = reinterpret_cast<const float4*>(pbuf);
  float4 s = p[i];
  #pragma unroll
  for (int sk = 1; sk < NSK; ++sk) {
    float4 v = p[(size_t)sk * (BL * NX / 4) + i];
    s.x += v.x; s.y += v.y; s.z += v.z; s.w += v.w;
  }
  reinterpret_cast<float4*>(xdbl)[i] = s;
  ushort4 H, L;
  H.x = f2b(s.x); L.x = f2b(s.x - b2f(H.x));
  H.y = f2b(s.y); L.y = f2b(s.y - b2f(H.y));
  H.z = f2b(s.z); L.z = f2b(s.z - b2f(H.z));
  H.w = f2b(s.w); L.w = f2b(s.w - b2f(H.w));
  reinterpret_cast<ushort4*>(xdh)[i] = H;
  reinterpret_cast<ushort4*>(xdl)[i] = L;
}

// ---------------------------------------------------------------------------
// Depthwise causal conv (D_CONV=4) + bias + SiLU, 4 elements/thread,
// vectorized loads + ushort4 plane writes.
// ---------------------------------------------------------------------------
__global__ __launch_bounds__(256) void conv_silu4(
    const float* __restrict__ xz, const float* __restrict__ w,
    const float* __restrict__ bias, u16* __restrict__ uch,
    u16* __restrict__ ucl) {
  int i = blockIdx.x * 256 + threadIdx.x;          // over BL*DI/4
  int d4 = (i << 2) & (DI - 1);
  int bl = i >> 9;                                 // (i*4)/DI
  int b  = bl >> 11;
  int l  = bl & (Lc - 1);
  const float4* wrow = reinterpret_cast<const float4*>(&w[d4 * 4]);
  float4 w0 = wrow[0], w1 = wrow[1], w2 = wrow[2], w3 = wrow[3];
  float4 a = *reinterpret_cast<const float4*>(&bias[d4]);
  #pragma unroll
  for (int k = 0; k < 4; ++k) {
    int ls = l - 3 + k;
    if (ls >= 0) {
      float4 xv = *reinterpret_cast<const float4*>(
          &xz[((size_t)(b * Lc + ls)) * (2 * DI) + d4]);
      a.x = fmaf(xv.x, (&w0.x)[k], a.x);
      a.y = fmaf(xv.y, (&w1.x)[k], a.y);
      a.z = fmaf(xv.z, (&w2.x)[k], a.z);
      a.w = fmaf(xv.w, (&w3.x)[k], a.w);
    }
  }
  a.x = a.x * __frcp_rn(1.f + __expf(-a.x));
  a.y = a.y * __frcp_rn(1.f + __expf(-a.y));
  a.z = a.z * __frcp_rn(1.f + __expf(-a.z));
  a.w = a.w * __frcp_rn(1.f + __expf(-a.w));
  ushort4 H, L;
  H.x = f2b(a.x); L.x = f2b(a.x - b2f(H.x));
  H.y = f2b(a.y); L.y = f2b(a.y - b2f(H.y));
  H.z = f2b(a.z); L.z = f2b(a.z - b2f(H.z));
  H.w = f2b(a.w); L.w = f2b(a.w - b2f(H.w));
  reinterpret_cast<ushort4*>(uch)[i] = H;
  reinterpret_cast<ushort4*>(ucl)[i] = L;
}

// ---------------------------------------------------------------------------
// Chunked scan, pass A (d-parallel): one thread per (b, d, chunk); 16 states
// in registers. Stores P[s] = exp2(Av2[s]*sum(dt)) and local final h[s].
// ---------------------------------------------------------------------------
__global__ __launch_bounds__(256) void scan_chunk_local(
    const float* __restrict__ delta, const u16* __restrict__ uch,
    const u16* __restrict__ ucl, const float* __restrict__ xdbl,
    const float* __restrict__ A_log, float* __restrict__ Pa,
    float* __restrict__ hA) {
  const int t = blockIdx.x * 256 + threadIdx.x;
  const int d = t & (DI - 1);
  const int b = (t >> 11) & (Bc - 1);
  const int c = t >> 12;
  const int bd = (b << 11) | d;

  float Av2[DS];
  {
    const float4* ap = reinterpret_cast<const float4*>(&A_log[(size_t)d * DS]);
    #pragma unroll
    for (int q = 0; q < 4; ++q) {
      float4 a = ap[q];
      Av2[4*q+0] = -LOG2E * __expf(a.x);
      Av2[4*q+1] = -LOG2E * __expf(a.y);
      Av2[4*q+2] = -LOG2E * __expf(a.z);
      Av2[4*q+3] = -LOG2E * __expf(a.w);
    }
  }
  const size_t rowbase = (size_t)(b * Lc + c * CH);
  const float* dp  = delta + rowbase * DI + d;
  const u16*   uhp = uch   + rowbase * DI + d;
  const u16*   ulp = ucl   + rowbase * DI + d;
  const float4* xp = reinterpret_cast<const float4*>(xdbl + rowbase * NX + DR);

  float h[DS] = {};
  float S = 0.f;
  float dt = dp[0];
  float ut = b2f(uhp[0]) + b2f(ulp[0]);
  float4 B0 = xp[0], B1 = xp[1], B2 = xp[2], B3 = xp[3];

  for (int l = 0; l < CH; ++l) {
    const int ln = (l + 1 < CH) ? l + 1 : l;
    float dtn = dp[ln * DI];
    float utn = b2f(uhp[ln * DI]) + b2f(ulp[ln * DI]);
    const float4* xn = xp + ln * (NX / 4);
    float4 B0n = xn[0], B1n = xn[1], B2n = xn[2], B3n = xn[3];

    float Bs[16];
    *reinterpret_cast<float4*>(&Bs[0])  = B0;
    *reinterpret_cast<float4*>(&Bs[4])  = B1;
    *reinterpret_cast<float4*>(&Bs[8])  = B2;
    *reinterpret_cast<float4*>(&Bs[12]) = B3;
    const float dtu = dt * ut;
    S += dt;
    #pragma unroll
    for (int s = 0; s < DS; ++s) {
      float dA = exp2f(dt * Av2[s]);
      h[s] = fmaf(dA, h[s], dtu * Bs[s]);
    }
    dt = dtn; ut = utn; B0 = B0n; B1 = B1n; B2 = B2n; B3 = B3n;
  }

  float4* Pp = reinterpret_cast<float4*>(&Pa[(size_t)c * BDS + (size_t)bd * DS]);
  float4* Hp = reinterpret_cast<float4*>(&hA[(size_t)c * BDS + (size_t)bd * DS]);
  #pragma unroll
  for (int q = 0; q < 4; ++q) {
    float4 pv, hv;
    pv.x = exp2f(Av2[4*q+0] * S); pv.y = exp2f(Av2[4*q+1] * S);
    pv.z = exp2f(Av2[4*q+2] * S); pv.w = exp2f(Av2[4*q+3] * S);
    hv.x = h[4*q+0]; hv.y = h[4*q+1]; hv.z = h[4*q+2]; hv.w = h[4*q+3];
    Pp[q] = pv; Hp[q] = hv;
  }
}

// ---------------------------------------------------------------------------
// Pass B: serial carry across chunks; h0 written in-place over Pa.
// ---------------------------------------------------------------------------
__global__ __launch_bounds__(256) void scan_chunk_carry(
    float* Pa_h0, const float* __restrict__ hA) {
  const int t = blockIdx.x * 256 + threadIdx.x; // over BDS
  float pa[NC], ha[NC];
  #pragma unroll
  for (int c = 0; c < NC; ++c) {
    pa[c] = Pa_h0[(size_t)c * BDS + t];
    ha[c] = hA[(size_t)c * BDS + t];
  }
  float h = 0.f;
  #pragma unroll
  for (int c = 0; c < NC; ++c) {
    Pa_h0[(size_t)c * BDS + t] = h;
    h = fmaf(pa[c], h, ha[c]);
  }
}

// ---------------------------------------------------------------------------
// Pass C (d-parallel): re-run local scan from carry-in h0, y in-register,
// skip + gate, write y hi/lo bf16 over the uc planes (element read strictly
// before written by its sole owner thread).
// ---------------------------------------------------------------------------
__global__ __launch_bounds__(256) void scan_chunk_final(
    const float* __restrict__ delta, const u16* uch, const u16* ucl,
    const float* __restrict__ xdbl, const float* __restrict__ xz,
    const float* __restrict__ A_log, const float* __restrict__ Dv,
    const float* __restrict__ h0, u16* yh, u16* yl) {
  const int t = blockIdx.x * 256 + threadIdx.x;
  const int d = t & (DI - 1);
  const int b = (t >> 11) & (Bc - 1);
  const int c = t >> 12;
  const int bd = (b << 11) | d;

  float Av2[DS];
  {
    const float4* ap = reinterpret_cast<const float4*>(&A_log[(size_t)d * DS]);
    #pragma unroll
    for (int q = 0; q < 4; ++q) {
      float4 a = ap[q];
      Av2[4*q+0] = -LOG2E * __expf(a.x);
      Av2[4*q+1] = -LOG2E * __expf(a.y);
      Av2[4*q+2] = -LOG2E * __expf(a.z);
      Av2[4*q+3] = -LOG2E * __expf(a.w);
    }
  }
  const float Dd = Dv[d];
  float h[DS];
  {
    const float4* hp = reinterpret_cast<const float4*>(&h0[(size_t)c * BDS + (size_t)bd * DS]);
    #pragma unroll
    for (int q = 0; q < 4; ++q) {
      float4 hv = hp[q];
      h[4*q+0] = hv.x; h[4*q+1] = hv.y; h[4*q+2] = hv.z; h[4*q+3] = hv.w;
    }
  }
  const size_t rowbase = (size_t)(b * Lc + c * CH);
  const float* dp  = delta + rowbase * DI + d;
  const u16*   uhp = uch   + rowbase * DI + d;
  const u16*   ulp = ucl   + rowbase * DI + d;
  const float* zp  = xz    + rowbase * (2 * DI) + DI + d;
  const float4* xp = reinterpret_cast<const float4*>(xdbl + rowbase * NX + DR);
  u16* yhp = yh + rowbase * DI + d;
  u16* ylp = yl + rowbase * DI + d;

  float dt = dp[0];
  float ut = b2f(uhp[0]) + b2f(ulp[0]);
  float zt = zp[0];
  float4 B0 = xp[0], B1 = xp[1], B2 = xp[2], B3 = xp[3];
  float4 C0 = xp[4], C1 = xp[5], C2 = xp[6], C3 = xp[7];

  for (int l = 0; l < CH; ++l) {
    const int ln = (l + 1 < CH) ? l + 1 : l;
    float dtn = dp[ln * DI];
    float utn = b2f(uhp[ln * DI]) + b2f(ulp[ln * DI]);
    float ztn = zp[ln * (2 * DI)];
    const float4* xn = xp + ln * (NX / 4);
    float4 B0n = xn[0], B1n = xn[1], B2n = xn[2], B3n = xn[3];
    float4 C0n = xn[4], C1n = xn[5], C2n = xn[6], C3n = xn[7];

    float Bs[16], Cs[16];
    *reinterpret_cast<float4*>(&Bs[0])  = B0;
    *reinterpret_cast<float4*>(&Bs[4])  = B1;
    *reinterpret_cast<float4*>(&Bs[8])  = B2;
    *reinterpret_cast<float4*>(&Bs[12]) = B3;
    *reinterpret_cast<float4*>(&Cs[0])  = C0;
    *reinterpret_cast<float4*>(&Cs[4])  = C1;
    *reinterpret_cast<float4*>(&Cs[8])  = C2;
    *reinterpret_cast<float4*>(&Cs[12]) = C3;
    const float dtu = dt * ut;
    float y0 = 0.f, y1 = 0.f;
    #pragma unroll
    for (int s = 0; s < DS; ++s) {
      float dA = exp2f(dt * Av2[s]);
      h[s] = fmaf(dA, h[s], dtu * Bs[s]);
      if (s & 1) y1 = fmaf(h[s], Cs[s], y1);
      else       y0 = fmaf(h[s], Cs[s], y0);
    }
    float gate = zt * __frcp_rn(1.f + exp2f(-LOG2E * zt));
    float y = (y0 + y1 + Dd * ut) * gate;
    u16 hh = f2b(y);
    yhp[l * DI] = hh;
    ylp[l * DI] = f2b(y - b2f(hh));

    dt = dtn; ut = utn; zt = ztn;
    B0 = B0n; B1 = B1n; B2 = B2n; B3 = B3n;
    C0 = C0n; C1 = C1n; C2 = C2n; C3 = C3n;
  }
}

// ---------------------------------------------------------------------------
extern "C" void kernel_launch(void* const* d_in, const int* in_sizes, int n_in,
                              void* d_out, int out_size, void* d_ws, size_t ws_size,
                              hipStream_t stream) {
  const float* x        = (const float*)d_in[0];
  const float* W_in     = (const float*)d_in[1];
  const float* conv_w   = (const float*)d_in[2];
  const float* conv_b   = (const float*)d_in[3];
  const float* W_xproj  = (const float*)d_in[4];
  const float* W_dtproj = (const float*)d_in[5];
  const float* dt_bias  = (const float*)d_in[6];
  const float* A_log    = (const float*)d_in[7];
  const float* Dv       = (const float*)d_in[8];
  const float* W_out    = (const float*)d_in[9];
  float* out = (float*)d_out;

  char* W = (char*)d_ws;
  size_t off = 0;
  float* xz  = (float*)(W + off);  off += (size_t)BL * 4096 * 4;    // 64 MB
  size_t delta_off = off;
  u16* xh   = (u16*)(W + off);     off += (size_t)BL * DM * 2;      // 8 MB
  u16* xl   = (u16*)(W + off);     off += (size_t)BL * DM * 2;      // 8 MB
  u16* Wih  = (u16*)(W + off);     off += (size_t)(2 * DI) * DM * 2;// 8 MB
  u16* Wil  = (u16*)(W + off);     off += (size_t)(2 * DI) * DM * 2;// 8 MB
  float* delta = (float*)(W + delta_off);  // 32 MB, aliases xh..Wil (dead post in_proj)
  u16* uch  = (u16*)(W + off);     off += (size_t)BL * DI * 2;      // 16 MB
  u16* ucl  = (u16*)(W + off);     off += (size_t)BL * DI * 2;      // 16 MB
  u16* Wxh  = (u16*)(W + off);     off += (size_t)128 * DI * 2;     // 0.5 MB (padded)
  u16* Wxl  = (u16*)(W + off);     off += (size_t)128 * DI * 2;
  float* xdbl = (float*)(W + off); off += (size_t)BL * NX * 4;      // 1.5 MB
  u16* xdh  = (u16*)(W + off);     off += (size_t)BL * NX * 2;
  u16* xdl  = (u16*)(W + off);     off += (size_t)BL * NX * 2;
  u16* Wdh  = (u16*)(W + off);     off += (size_t)DI * DR * 2;
  u16* Wdl  = (u16*)(W + off);     off += (size_t)DI * DR * 2;
  u16* Woh  = (u16*)(W + off);     off += (size_t)DM * DI * 2;      // 4 MB
  u16* Wol  = (u16*)(W + off);     off += (size_t)DM * DI * 2;      // 4 MB
  float* Pa = (float*)(W + off);   off += (size_t)NC * BDS * 4;     // 8 MB
  float* hA = (float*)(W + off);   off += (size_t)NC * BDS * 4;     // 8 MB
  float* h0 = Pa;                  // pass B writes h0 in-place over Pa
  float* pbuf = Pa;                // x_proj split-K partials (12.6 MB, dead
                                   // before scan_local writes Pa/hA)
  u16* yh = uch;                   // pass C writes y over uc planes (safe)
  u16* yl = ucl;

  // 0) conversions to bf16 hi/lo planes
  cvt_hilo<<<(BL * DM / 4 + 255) / 256, 256, 0, stream>>>(x, xh, xl, BL * DM / 4);
  cvt_hilo<<<(2 * DI * DM / 4 + 255) / 256, 256, 0, stream>>>(W_in, Wih, Wil, 2 * DI * DM / 4);
  cvt_pad_wx<<<(128 * DI / 4) / 256, 256, 0, stream>>>(W_xproj, Wxh, Wxl);
  cvt_hilo<<<(DI * DR / 4 + 255) / 256, 256, 0, stream>>>(W_dtproj, Wdh, Wdl, DI * DR / 4);
  cvt_hilo<<<(DM * DI / 4 + 255) / 256, 256, 0, stream>>>(W_out, Woh, Wol, DM * DI / 4);

  // 1) in_proj: xz = x @ W_in^T   (M=4096, N=4096, K=1024)
  gemm_mfma<0><<<dim3(BL / 128, (2 * DI) / 128, 1), 512, 0, stream>>>(
      xh, xl, Wih, Wil, nullptr, xz, BL, 2 * DI, DM, DM, DM, 2 * DI, 0);

  // 2) depthwise causal conv + SiLU -> uc hi/lo planes (4 elems/thread)
  conv_silu4<<<(BL * DI / 4) / 256, 256, 0, stream>>>(xz, conv_w, conv_b, uch, ucl);

  // 3) x_proj split-K=8: partials pbuf[sk][BL][96] = u_c @ W_xproj^T slices
  gemm_mfma<0><<<dim3(BL / 128, 1, NSK), 512, 0, stream>>>(
      uch, ucl, Wxh, Wxl, nullptr, pbuf, BL, NX, DI / NSK, DI, DI, NX,
      (size_t)BL * NX);

  // 3b) reduce partials -> xdbl fp32 + hi/lo planes (fused cvt)
  xproj_reduce<<<(BL * NX / 4) / 256, 256, 0, stream>>>(pbuf, xdbl, xdh, xdl);

  // 4) dt_proj + softplus: delta = softplus(xdbl[:, :64] @ W_dtproj^T + bias)
  gemm_mfma<1><<<dim3(BL / 128, DI / 128, 1), 512, 0, stream>>>(
      xdh, xdl, Wdh, Wdl, dt_bias, delta, BL, DI, DR, NX, DR, DI, 0);

  // 5) chunked selective scan (3 passes, d-parallel A/C)
  scan_chunk_local<<<(Bc * DI * NC) / 256, 256, 0, stream>>>(
      delta, uch, ucl, xdbl, A_log, Pa, hA);
  scan_chunk_carry<<<BDS / 256, 256, 0, stream>>>(Pa, hA);
  scan_chunk_final<<<(Bc * DI * NC) / 256, 256, 0, stream>>>(
      delta, uch, ucl, xdbl, xz, A_log, Dv, h0, yh, yl);

  // 6) out_proj: out = y @ W_out^T  (M=4096, N=1024, K=2048)
  gemm_mfma<0><<<dim3(BL / 128, DM / 128, 1), 512, 0, stream>>>(
      yh, yl, Woh, Wol, nullptr, out, BL, DM, DI, DI, DI, DM, 0);
}